// Round 4
// baseline (1626.752 us; speedup 1.0000x reference)
//
#include <hip/hip_runtime.h>
#include <hip/hip_fp16.h>

// ---------------------------------------------------------------------------
// Fused persistent-kernel MLP: 10 x (Linear -> BatchNorm(train) -> tanh) +
// Linear -> sigmoid, B = 2^20 rows.
//
// R4 vs R3: compute path UNCHANGED. Sync machinery rebuilt — R3's barrier had
// all 8 "split" counters in ONE cache line, with 1024 RMW arrivals + 1024
// pollers x 8 loads on that line per barrier, plus per-block gstats
// re-reduction (16 far loads x 1024 blocks x 10 layers). Fix:
//   * arrival counters / stat slots / flags padded to separate 128-256B lines
//   * single-reducer barrier: block 0 polls arrivals, reduces gstats once,
//     publishes scale/shift (scsh) + 8 replicated generation flags;
//     other blocks poll ONE read-only flag line with s_sleep backoff.
// ---------------------------------------------------------------------------

#define NBLK 1024
#define NTHR 256
#define RPT  4
#define BATCHN 1048576
#define NREP 32        // LDS stat replicas (stride 49 odd -> bank bijection)
#define SSTR 49
#define GSLOTS 8       // arrival/stat contention splitting
#define GPAD 64        // floats per gstats slot (256B line-pad)
#define BARPAD 32      // uints per bar/flag slot (128B line-pad)

static_assert(NBLK * NTHR * RPT == BATCHN, "row coverage");

static constexpr int D_[12] = {64, 4, 20, 10, 10, 10, 10, 10, 5, 5, 5, 1};

static constexpr int np_(int d) { return (d + 1) / 2; }
static constexpr int w2offc(int l) {  // float2 offset of layer l (l>=1) weights
    int o = 0;
    for (int k = 1; k < l; ++k) o += D_[k + 1] * np_(D_[k]);
    return o;
}
static constexpr int boffc(int l) {
    int o = 0;
    for (int k = 0; k < l; ++k) o += D_[k + 1];
    return o;
}
static constexpr int W2TOT = w2offc(11);
static constexpr int BTOT = boffc(11);
static constexpr int GTOT = boffc(10);

struct Params {
    const float* x;
    const float* W[11];
    const float* b[11];
    const float* g[10];
    const float* bt[10];
    float* out;
    float* gstats;   // [10][GSLOTS][GPAD]
    unsigned* bar;   // [10][GSLOTS][BARPAD]
    unsigned* flags; // [10][GSLOTS][BARPAD]
    float* scsh;     // [10][64]: per layer, (sc,sh) pairs for tid<DOUT
};

__device__ __forceinline__ float fast_tanh(float x) {
    float e = exp2f(x * 2.8853900817779268f);
    return 1.0f - __fdividef(2.0f, e + 1.0f);
}

// ---- staging ----------------------------------------------------------------
template <int L>
__device__ __forceinline__ void stageW2(const Params& p, float2* lW2, int tid) {
    constexpr int DIN = D_[L], DOUT = D_[L + 1], NP = np_(DIN), WO = w2offc(L);
    for (int i = tid; i < DOUT * NP; i += NTHR) {
        const int o = i / NP, cp = i - o * NP;
        const int c0 = 2 * cp, c1 = c0 + 1;
        const float w0 = p.W[L][o * DIN + c0];
        const float w1 = (c1 < DIN) ? p.W[L][o * DIN + c1] : 0.0f;
        lW2[WO + i] = make_float2(w0, w1);
    }
}

template <int L>
__device__ __forceinline__ void stageB(const Params& p, float* lB, float* lG,
                                       float* lT, int tid) {
    constexpr int DOUT = D_[L + 1], BO = boffc(L);
    if (tid < DOUT) {
        lB[BO + tid] = p.b[L][tid];
        if (L < 10) {
            lG[BO + tid] = p.g[L][tid];
            lT[BO + tid] = p.bt[L][tid];
        }
    }
}

// ---- fold replicas -> global stats -> flag barrier -> scale/shift -> tanh ---
template <int L, int DOUT>
__device__ __forceinline__ void finish_bn(const Params& p, __half2 (&h)[RPT][10],
                                          const float* lG, const float* lT,
                                          float* bsum, float* lsc, float* lsh,
                                          int tid, int bslot, bool b0) {
    __syncthreads();   // all LDS stat atomics done
    if (tid < 2 * DOUT) {
        const int idx = (tid < DOUT) ? tid : (24 + (tid - DOUT));
        float v = 0.0f;
        for (int r = 0; r < NREP; ++r) v += bsum[r * SSTR + idx];
        atomicAdd(&p.gstats[(L * GSLOTS + bslot) * GPAD + idx], v);
    }
    __syncthreads();   // deposits globally performed before arrival

    if (b0) {
        // ---- designated reducer: block 0 ----
        if (tid == 0) {
            __hip_atomic_fetch_add(&p.bar[(L * GSLOTS + 0) * BARPAD], 1u,
                                   __ATOMIC_RELEASE, __HIP_MEMORY_SCOPE_AGENT);
            unsigned tot;
            do {
                tot = 0;
                for (int q = 0; q < GSLOTS; ++q)
                    tot += __hip_atomic_load(&p.bar[(L * GSLOTS + q) * BARPAD],
                                             __ATOMIC_RELAXED, __HIP_MEMORY_SCOPE_AGENT);
                if (tot < NBLK) __builtin_amdgcn_s_sleep(4);
            } while (tot < NBLK);
            for (int q = 0; q < GSLOTS; ++q)
                (void)__hip_atomic_load(&p.bar[(L * GSLOTS + q) * BARPAD],
                                        __ATOMIC_ACQUIRE, __HIP_MEMORY_SCOPE_AGENT);
        }
        __syncthreads();
        if (tid < DOUT) {
            float s = 0.0f, s2 = 0.0f;
            for (int q = 0; q < GSLOTS; ++q) {
                s += __hip_atomic_load(&p.gstats[(L * GSLOTS + q) * GPAD + tid],
                                       __ATOMIC_RELAXED, __HIP_MEMORY_SCOPE_AGENT);
                s2 += __hip_atomic_load(&p.gstats[(L * GSLOTS + q) * GPAD + 24 + tid],
                                        __ATOMIC_RELAXED, __HIP_MEMORY_SCOPE_AGENT);
            }
            constexpr float inv = 1.0f / (float)BATCHN;
            const float m = s * inv;
            const float var = fmaxf(s2 * inv - m * m, 0.0f);
            const float scv = lG[boffc(L) + tid] * rsqrtf(var + 1e-5f);
            const float shv = lT[boffc(L) + tid] - m * scv;
            lsc[tid] = scv;
            lsh[tid] = shv;
            __hip_atomic_store(&p.scsh[L * 64 + 2 * tid], scv,
                               __ATOMIC_RELAXED, __HIP_MEMORY_SCOPE_AGENT);
            __hip_atomic_store(&p.scsh[L * 64 + 2 * tid + 1], shv,
                               __ATOMIC_RELAXED, __HIP_MEMORY_SCOPE_AGENT);
        }
        __syncthreads();   // scsh stores drained (vmcnt) before flag release
        if (tid < GSLOTS)
            __hip_atomic_store(&p.flags[(L * GSLOTS + tid) * BARPAD], 1u,
                               __ATOMIC_RELEASE, __HIP_MEMORY_SCOPE_AGENT);
    } else {
        // ---- everyone else: arrive, then poll ONE replicated flag line ----
        if (tid == 0) {
            __hip_atomic_fetch_add(&p.bar[(L * GSLOTS + bslot) * BARPAD], 1u,
                                   __ATOMIC_RELEASE, __HIP_MEMORY_SCOPE_AGENT);
            while (__hip_atomic_load(&p.flags[(L * GSLOTS + bslot) * BARPAD],
                                     __ATOMIC_ACQUIRE, __HIP_MEMORY_SCOPE_AGENT) == 0u)
                __builtin_amdgcn_s_sleep(8);
        }
        __syncthreads();
        if (tid < DOUT) {
            lsc[tid] = __hip_atomic_load(&p.scsh[L * 64 + 2 * tid],
                                         __ATOMIC_RELAXED, __HIP_MEMORY_SCOPE_AGENT);
            lsh[tid] = __hip_atomic_load(&p.scsh[L * 64 + 2 * tid + 1],
                                         __ATOMIC_RELAXED, __HIP_MEMORY_SCOPE_AGENT);
        }
        __syncthreads();
    }

    // normalize + tanh, in place on packed h
#pragma unroll
    for (int j = 0; j < RPT; ++j) {
#pragma unroll
        for (int op = 0; op < (DOUT + 1) / 2; ++op) {
            const int o0 = 2 * op, o1 = o0 + 1;
            const float t0 = fast_tanh(fmaf(__low2float(h[j][op]), lsc[o0], lsh[o0]));
            const float t1 = (o1 < DOUT)
                ? fast_tanh(fmaf(__high2float(h[j][op]), lsc[o1], lsh[o1]))
                : 0.0f;
            h[j][op] = __floats2half2_rn(t0, t1);
        }
    }
}

// ---- hidden layer L=1..9: Linear(ain) -> stats -> h(f16) -> BN+tanh ---------
template <int L>
__device__ __forceinline__ void layer_h(const Params& p, const float2* lW2,
                                        const float* lB, const float* lG,
                                        const float* lT, float* bsum,
                                        float* lsc, float* lsh,
                                        const __half2 (&ain)[RPT][10],
                                        __half2 (&hout)[RPT][10],
                                        int tid, int bslot, bool b0) {
    constexpr int DIN = D_[L], DOUT = D_[L + 1], NP = np_(DIN);
    constexpr int WO = w2offc(L), BO = boffc(L);
    __syncthreads();   // previous layer's bsum reads + lsc/lsh reads done
    for (int i = tid; i < NREP * SSTR; i += NTHR) bsum[i] = 0.0f;
    __syncthreads();
    const int rep = (tid & 31) * SSTR;

#pragma unroll
    for (int op = 0; op < DOUT / 2; ++op) {
        const int o0 = 2 * op, o1 = o0 + 1;
        float a0[RPT], a1[RPT];
#pragma unroll
        for (int j = 0; j < RPT; ++j) { a0[j] = lB[BO + o0]; a1[j] = lB[BO + o1]; }
#pragma unroll
        for (int cp = 0; cp < NP; ++cp) {
            const float2 w0 = lW2[WO + o0 * NP + cp];
            const float2 w1 = lW2[WO + o1 * NP + cp];
#pragma unroll
            for (int j = 0; j < RPT; ++j) {
                const float x0 = __low2float(ain[j][cp]);
                const float x1 = __high2float(ain[j][cp]);
                a0[j] = fmaf(w0.x, x0, fmaf(w0.y, x1, a0[j]));
                a1[j] = fmaf(w1.x, x0, fmaf(w1.y, x1, a1[j]));
            }
        }
        const float s0 = (a0[0] + a0[1]) + (a0[2] + a0[3]);
        const float q0 = fmaf(a0[0], a0[0], fmaf(a0[1], a0[1], fmaf(a0[2], a0[2], a0[3] * a0[3])));
        const float s1 = (a1[0] + a1[1]) + (a1[2] + a1[3]);
        const float q1 = fmaf(a1[0], a1[0], fmaf(a1[1], a1[1], fmaf(a1[2], a1[2], a1[3] * a1[3])));
        atomicAdd(&bsum[rep + o0], s0);      atomicAdd(&bsum[rep + 24 + o0], q0);
        atomicAdd(&bsum[rep + o1], s1);      atomicAdd(&bsum[rep + 24 + o1], q1);
#pragma unroll
        for (int j = 0; j < RPT; ++j) hout[j][op] = __floats2half2_rn(a0[j], a1[j]);
    }
    if constexpr (DOUT & 1) {
        constexpr int o0 = DOUT - 1;
        float a0[RPT];
#pragma unroll
        for (int j = 0; j < RPT; ++j) a0[j] = lB[BO + o0];
#pragma unroll
        for (int cp = 0; cp < NP; ++cp) {
            const float2 w0 = lW2[WO + o0 * NP + cp];
#pragma unroll
            for (int j = 0; j < RPT; ++j)
                a0[j] = fmaf(w0.x, __low2float(ain[j][cp]),
                        fmaf(w0.y, __high2float(ain[j][cp]), a0[j]));
        }
        const float s0 = (a0[0] + a0[1]) + (a0[2] + a0[3]);
        const float q0 = fmaf(a0[0], a0[0], fmaf(a0[1], a0[1], fmaf(a0[2], a0[2], a0[3] * a0[3])));
        atomicAdd(&bsum[rep + o0], s0);      atomicAdd(&bsum[rep + 24 + o0], q0);
#pragma unroll
        for (int j = 0; j < RPT; ++j) hout[j][DOUT / 2] = __floats2half2_rn(a0[j], 0.0f);
    }
    finish_bn<L, D_[L + 1]>(p, hout, lG, lT, bsum, lsc, lsh, tid, bslot, b0);
}

// ---------------------------------------------------------------------------
__global__ void
__attribute__((amdgpu_flat_work_group_size(NTHR, NTHR), amdgpu_waves_per_eu(4, 4)))
mlp_fused(Params p) {
    __shared__ __align__(16) float lW0[256];     // layer-0 weights f32 [4][64]
    __shared__ __align__(8) float2 lW2[W2TOT];   // layers 1..10, paired f32
    __shared__ float lB[BTOT], lG[GTOT], lT[GTOT];
    __shared__ float bsum[NREP * SSTR];
    __shared__ float lsc[20], lsh[20];

    const int tid = threadIdx.x;
    const int bslot = blockIdx.x & (GSLOTS - 1);
    const bool b0 = (blockIdx.x == 0);

    for (int i = tid; i < 256; i += NTHR) lW0[i] = p.W[0][i];
    stageW2<1>(p, lW2, tid);  stageW2<2>(p, lW2, tid);  stageW2<3>(p, lW2, tid);
    stageW2<4>(p, lW2, tid);  stageW2<5>(p, lW2, tid);  stageW2<6>(p, lW2, tid);
    stageW2<7>(p, lW2, tid);  stageW2<8>(p, lW2, tid);  stageW2<9>(p, lW2, tid);
    stageW2<10>(p, lW2, tid);
    stageB<0>(p, lB, lG, lT, tid);  stageB<1>(p, lB, lG, lT, tid);
    stageB<2>(p, lB, lG, lT, tid);  stageB<3>(p, lB, lG, lT, tid);
    stageB<4>(p, lB, lG, lT, tid);  stageB<5>(p, lB, lG, lT, tid);
    stageB<6>(p, lB, lG, lT, tid);  stageB<7>(p, lB, lG, lT, tid);
    stageB<8>(p, lB, lG, lT, tid);  stageB<9>(p, lB, lG, lT, tid);
    stageB<10>(p, lB, lG, lT, tid);
    __syncthreads();

    const int rowbase = blockIdx.x * (NTHR * RPT) + tid;  // + j*NTHR, coalesced

    __half2 A[RPT][10], B[RPT][10];   // ping-pong packed activations / pre-BN h

    // ---- layer 0: x(64) -> 4, streamed from HBM, f32 accumulate ----
    {
        float acc[RPT][4];
#pragma unroll
        for (int j = 0; j < RPT; ++j)
#pragma unroll
            for (int o = 0; o < 4; ++o) acc[j][o] = lB[boffc(0) + o];
#pragma unroll
        for (int c = 0; c < 16; ++c) {
            const float4 w0 = *(const float4*)&lW0[0 * 64 + c * 4];
            const float4 w1 = *(const float4*)&lW0[1 * 64 + c * 4];
            const float4 w2 = *(const float4*)&lW0[2 * 64 + c * 4];
            const float4 w3 = *(const float4*)&lW0[3 * 64 + c * 4];
#pragma unroll
            for (int j = 0; j < RPT; ++j) {
                const float4 xv = *(const float4*)(p.x + (size_t)(rowbase + j * NTHR) * 64 + c * 4);
                acc[j][0] = fmaf(w0.x, xv.x, fmaf(w0.y, xv.y, fmaf(w0.z, xv.z, fmaf(w0.w, xv.w, acc[j][0]))));
                acc[j][1] = fmaf(w1.x, xv.x, fmaf(w1.y, xv.y, fmaf(w1.z, xv.z, fmaf(w1.w, xv.w, acc[j][1]))));
                acc[j][2] = fmaf(w2.x, xv.x, fmaf(w2.y, xv.y, fmaf(w2.z, xv.z, fmaf(w2.w, xv.w, acc[j][2]))));
                acc[j][3] = fmaf(w3.x, xv.x, fmaf(w3.y, xv.y, fmaf(w3.z, xv.z, fmaf(w3.w, xv.w, acc[j][3]))));
            }
        }
        __syncthreads();
        for (int i = tid; i < NREP * SSTR; i += NTHR) bsum[i] = 0.0f;
        __syncthreads();
        const int rep = (tid & 31) * SSTR;
#pragma unroll
        for (int d = 0; d < 4; ++d) {
            const float s = (acc[0][d] + acc[1][d]) + (acc[2][d] + acc[3][d]);
            const float q = fmaf(acc[0][d], acc[0][d], fmaf(acc[1][d], acc[1][d],
                            fmaf(acc[2][d], acc[2][d], acc[3][d] * acc[3][d])));
            atomicAdd(&bsum[rep + d], s);
            atomicAdd(&bsum[rep + 24 + d], q);
        }
#pragma unroll
        for (int j = 0; j < RPT; ++j) {
            A[j][0] = __floats2half2_rn(acc[j][0], acc[j][1]);
            A[j][1] = __floats2half2_rn(acc[j][2], acc[j][3]);
        }
        finish_bn<0, 4>(p, A, lG, lT, bsum, lsc, lsh, tid, bslot, b0);
    }

    // ---- layers 1..9 (ping-pong A/B) ----
    layer_h<1>(p, lW2, lB, lG, lT, bsum, lsc, lsh, A, B, tid, bslot, b0);
    layer_h<2>(p, lW2, lB, lG, lT, bsum, lsc, lsh, B, A, tid, bslot, b0);
    layer_h<3>(p, lW2, lB, lG, lT, bsum, lsc, lsh, A, B, tid, bslot, b0);
    layer_h<4>(p, lW2, lB, lG, lT, bsum, lsc, lsh, B, A, tid, bslot, b0);
    layer_h<5>(p, lW2, lB, lG, lT, bsum, lsc, lsh, A, B, tid, bslot, b0);
    layer_h<6>(p, lW2, lB, lG, lT, bsum, lsc, lsh, B, A, tid, bslot, b0);
    layer_h<7>(p, lW2, lB, lG, lT, bsum, lsc, lsh, A, B, tid, bslot, b0);
    layer_h<8>(p, lW2, lB, lG, lT, bsum, lsc, lsh, B, A, tid, bslot, b0);
    layer_h<9>(p, lW2, lB, lG, lT, bsum, lsc, lsh, A, B, tid, bslot, b0);

    // ---- layer 10: 5 -> 1, sigmoid, store (reads B; B[j][2].y == 0) ----
    {
        constexpr int WO = w2offc(10), BO = boffc(10);
#pragma unroll
        for (int j = 0; j < RPT; ++j) {
            float a = lB[BO];
#pragma unroll
            for (int cp = 0; cp < 3; ++cp) {
                const float2 w = lW2[WO + cp];
                a = fmaf(w.x, __low2float(B[j][cp]),
                    fmaf(w.y, __high2float(B[j][cp]), a));
            }
            const float e = exp2f(a * -1.4426950408889634f);
            p.out[rowbase + j * NTHR] = __fdividef(1.0f, 1.0f + e);
        }
    }
}

// zero stats + barrier + flag regions each call (ws is NOT re-poisoned
// between graph replays, so this must run every launch)
__global__ void init_ws(float* gstats, unsigned* bar, unsigned* flags) {
    int i = threadIdx.x + blockIdx.x * blockDim.x;
    if (i < 10 * GSLOTS * GPAD) gstats[i] = 0.0f;
    if (i < 10 * GSLOTS * BARPAD) { bar[i] = 0u; flags[i] = 0u; }
}

extern "C" void kernel_launch(void* const* d_in, const int* in_sizes, int n_in,
                              void* d_out, int out_size, void* d_ws, size_t ws_size,
                              hipStream_t stream) {
    Params p;
    p.x = (const float*)d_in[0];
    int k = 1;
    for (int l = 0; l < 11; ++l) {
        p.W[l] = (const float*)d_in[k++];
        p.b[l] = (const float*)d_in[k++];
        if (l < 10) {
            p.g[l] = (const float*)d_in[k++];
            p.bt[l] = (const float*)d_in[k++];
        }
    }
    p.out = (float*)d_out;
    char* ws = (char*)d_ws;
    p.gstats = (float*)ws;                                   // 10*8*64 f = 20480B
    p.bar    = (unsigned*)(ws + 20480);                      // 10*8*32 u = 10240B
    p.flags  = (unsigned*)(ws + 20480 + 10240);              // 10*8*32 u = 10240B
    p.scsh   = (float*)(ws + 20480 + 10240 + 10240);         // 10*64 f  =  2560B

    init_ws<<<dim3(20), dim3(256), 0, stream>>>(p.gstats, p.bar, p.flags);
    mlp_fused<<<dim3(NBLK), dim3(NTHR), 0, stream>>>(p);
}

// Round 5
// 1180.527 us; speedup vs baseline: 1.3780x; 1.3780x over previous
//
#include <hip/hip_runtime.h>
#include <hip/hip_fp16.h>

// ---------------------------------------------------------------------------
// Multi-kernel MLP: 12 graph-captured launches, kernel boundary = global sync.
//   layer0   : x(f32,64) -> h0(f16,4)  + partial stats of h0
//   layer_mid<L>, L=1..9 : apply BN_{L-1}+tanh on the fly, linear, emit
//                          h_L (packed f16) + partial stats of h_L
//   layer10  : apply BN_9+tanh, linear 5->1, sigmoid -> out(f32)
// Stats: LDS replica accumulators -> 64 padded global atomic slots ->
// last-finished block (acq_rel counter) reduces slots and writes scale/shift
// for the NEXT kernel. No device-wide barriers, no co-residency requirement.
// R5 rationale: R1-R4 persistent kernel was stuck at ~1.4ms regardless of
// spill volume or barrier design; this design has tiny per-thread state
// (no spills), 2048-block parallelism, and L3-resident intermediates.
// ---------------------------------------------------------------------------

#define NBLK 2048
#define NTHR 256
#define RPT  2
#define BATCHN 1048576
#define NREP 32        // LDS stat replicas (stride 49 odd -> bank bijection)
#define SSTR 49
#define NSLOT 64       // global stat slots (contention: 2048/64=32 adds/slot)
#define SLOTW 48       // floats per slot: [0..23]=sum, [24..47]=sumsq (192B)

static_assert(NBLK * NTHR * RPT == BATCHN, "row coverage");

static constexpr int D_[12] = {64, 4, 20, 10, 10, 10, 10, 10, 5, 5, 5, 1};

__device__ __forceinline__ float fast_tanh(float x) {
    // tanh(x) = 1 - 2/(exp2(2*log2e*x)+1); exp2f -> v_exp_f32
    const float e = exp2f(x * 2.8853900817779268f);
    return 1.0f - __fdividef(2.0f, e + 1.0f);
}

// ---- per-layer stats finalization ------------------------------------------
// bsum: LDS replicas; gslots: this layer's [NSLOT][SLOTW] global slots;
// counter: this layer's done-counter; writes scsh_out[2*f], [2*f+1].
template <int DOUT>
__device__ __forceinline__ void stats_finish(float* bsum, float* __restrict__ gslots,
                                             unsigned* __restrict__ counter,
                                             const float* __restrict__ g,
                                             const float* __restrict__ bt,
                                             float* __restrict__ scsh_out,
                                             int tid, int bid) {
    __syncthreads();   // all LDS stat atomics done
    if (tid < 2 * DOUT) {
        const int idx = (tid < DOUT) ? tid : (24 + (tid - DOUT));
        float v = 0.0f;
        for (int r = 0; r < NREP; ++r) v += bsum[r * SSTR + idx];
        atomicAdd(&gslots[(bid & (NSLOT - 1)) * SLOTW + idx], v);   // device-scope
    }
    __syncthreads();   // block's slot adds issued before counter bump
    __shared__ int lastflag;
    if (tid == 0) {
        const unsigned old = __hip_atomic_fetch_add(counter, 1u, __ATOMIC_ACQ_REL,
                                                    __HIP_MEMORY_SCOPE_AGENT);
        lastflag = (old == (unsigned)(NBLK - 1));
    }
    __syncthreads();
    if (lastflag && tid < DOUT) {
        float s = 0.0f, s2 = 0.0f;
        for (int q = 0; q < NSLOT; ++q) {
            s  += __hip_atomic_load(&gslots[q * SLOTW + tid],
                                    __ATOMIC_RELAXED, __HIP_MEMORY_SCOPE_AGENT);
            s2 += __hip_atomic_load(&gslots[q * SLOTW + 24 + tid],
                                    __ATOMIC_RELAXED, __HIP_MEMORY_SCOPE_AGENT);
        }
        constexpr float inv = 1.0f / (float)BATCHN;
        const float m = s * inv;
        const float var = fmaxf(s2 * inv - m * m, 0.0f);
        const float sc = g[tid] * rsqrtf(var + 1e-5f);
        scsh_out[2 * tid]     = sc;                 // visible at kernel boundary
        scsh_out[2 * tid + 1] = bt[tid] - m * sc;
    }
}

// ---- layer 0: x(64) -> h0(4), f32 accumulate, emit packed f16 --------------
__global__ void layer0(const float* __restrict__ x, __half2* __restrict__ hout,
                       const float* __restrict__ W, const float* __restrict__ b,
                       const float* __restrict__ g, const float* __restrict__ bt,
                       float* __restrict__ scsh_out, float* __restrict__ gslots,
                       unsigned* __restrict__ counter) {
    __shared__ __align__(16) float lw0[256];   // [4][64]
    __shared__ float lb[4];
    __shared__ float bsum[NREP * SSTR];
    const int tid = threadIdx.x, bid = blockIdx.x;
    lw0[tid] = W[tid];                         // NTHR == 256 == 4*64
    if (tid < 4) lb[tid] = b[tid];
    for (int i = tid; i < NREP * SSTR; i += NTHR) bsum[i] = 0.0f;
    __syncthreads();

    const int rowbase = bid * (NTHR * RPT) + tid;
    float acc[RPT][4];
#pragma unroll
    for (int j = 0; j < RPT; ++j)
#pragma unroll
        for (int o = 0; o < 4; ++o) acc[j][o] = lb[o];
#pragma unroll
    for (int c = 0; c < 16; ++c) {
        const float4 w0 = *(const float4*)&lw0[0 * 64 + c * 4];
        const float4 w1 = *(const float4*)&lw0[1 * 64 + c * 4];
        const float4 w2 = *(const float4*)&lw0[2 * 64 + c * 4];
        const float4 w3 = *(const float4*)&lw0[3 * 64 + c * 4];
#pragma unroll
        for (int j = 0; j < RPT; ++j) {
            const float4 xv = *(const float4*)(x + (size_t)(rowbase + j * NTHR) * 64 + c * 4);
            acc[j][0] = fmaf(w0.x, xv.x, fmaf(w0.y, xv.y, fmaf(w0.z, xv.z, fmaf(w0.w, xv.w, acc[j][0]))));
            acc[j][1] = fmaf(w1.x, xv.x, fmaf(w1.y, xv.y, fmaf(w1.z, xv.z, fmaf(w1.w, xv.w, acc[j][1]))));
            acc[j][2] = fmaf(w2.x, xv.x, fmaf(w2.y, xv.y, fmaf(w2.z, xv.z, fmaf(w2.w, xv.w, acc[j][2]))));
            acc[j][3] = fmaf(w3.x, xv.x, fmaf(w3.y, xv.y, fmaf(w3.z, xv.z, fmaf(w3.w, xv.w, acc[j][3]))));
        }
    }
    const int rep = (tid & 31) * SSTR;
#pragma unroll
    for (int d = 0; d < 4; ++d) {
        const float s = acc[0][d] + acc[1][d];
        const float q = fmaf(acc[0][d], acc[0][d], acc[1][d] * acc[1][d]);
        atomicAdd(&bsum[rep + d], s);
        atomicAdd(&bsum[rep + 24 + d], q);
    }
#pragma unroll
    for (int j = 0; j < RPT; ++j) {
        __half2* wp = hout + (size_t)(rowbase + j * NTHR) * 2;
        wp[0] = __floats2half2_rn(acc[j][0], acc[j][1]);
        wp[1] = __floats2half2_rn(acc[j][2], acc[j][3]);
    }
    stats_finish<4>(bsum, gslots, counter, g, bt, scsh_out, tid, bid);
}

// ---- layers 1..9: BN_{L-1}+tanh fused in, linear, emit h_L packed f16 ------
template <int L>
__global__ void layer_mid(const __half2* __restrict__ hin, __half2* __restrict__ hout,
                          const float* __restrict__ W, const float* __restrict__ b,
                          const float* __restrict__ g, const float* __restrict__ bt,
                          const float* __restrict__ scsh_prev,
                          float* __restrict__ scsh_out,
                          float* __restrict__ gslots, unsigned* __restrict__ counter) {
    constexpr int DIN = D_[L], DOUT = D_[L + 1];
    constexpr int NPI = (DIN + 1) / 2, NPO = (DOUT + 1) / 2;
    __shared__ float2 lw[DOUT * NPI];
    __shared__ float lb[DOUT], lsc[DIN], lsh[DIN];
    __shared__ float bsum[NREP * SSTR];
    const int tid = threadIdx.x, bid = blockIdx.x;
    for (int i = tid; i < DOUT * NPI; i += NTHR) {
        const int o = i / NPI, cp = i - o * NPI;
        const float w0 = W[o * DIN + 2 * cp];
        const float w1 = (2 * cp + 1 < DIN) ? W[o * DIN + 2 * cp + 1] : 0.0f;
        lw[i] = make_float2(w0, w1);
    }
    if (tid < DOUT) lb[tid] = b[tid];
    if (tid < DIN) { lsc[tid] = scsh_prev[2 * tid]; lsh[tid] = scsh_prev[2 * tid + 1]; }
    for (int i = tid; i < NREP * SSTR; i += NTHR) bsum[i] = 0.0f;
    __syncthreads();

    const int rowbase = bid * (NTHR * RPT) + tid;

    // load h_{L-1}, apply BN+tanh, repack to f16 pairs
    __half2 a2[RPT][NPI];
#pragma unroll
    for (int j = 0; j < RPT; ++j) {
        const __half2* rp = hin + (size_t)(rowbase + j * NTHR) * NPI;
#pragma unroll
        for (int cp = 0; cp < NPI; ++cp) {
            const __half2 hv = rp[cp];
            const float t0 = fast_tanh(fmaf(__low2float(hv), lsc[2 * cp], lsh[2 * cp]));
            const float t1 = (2 * cp + 1 < DIN)
                ? fast_tanh(fmaf(__high2float(hv), lsc[2 * cp + 1], lsh[2 * cp + 1]))
                : 0.0f;
            a2[j][cp] = __floats2half2_rn(t0, t1);
        }
    }

    const int rep = (tid & 31) * SSTR;
    __half2 hp[RPT][NPO];
#pragma unroll
    for (int op = 0; op < NPO; ++op) {
        const int o0 = 2 * op, o1 = 2 * op + 1;
        float a0[RPT], a1[RPT];
#pragma unroll
        for (int j = 0; j < RPT; ++j) {
            a0[j] = lb[o0];
            a1[j] = (o1 < DOUT) ? lb[o1] : 0.0f;
        }
#pragma unroll
        for (int cp = 0; cp < NPI; ++cp) {
            const float2 w0 = lw[o0 * NPI + cp];
            const float2 w1 = (o1 < DOUT) ? lw[o1 * NPI + cp] : make_float2(0.0f, 0.0f);
#pragma unroll
            for (int j = 0; j < RPT; ++j) {
                const float x0 = __low2float(a2[j][cp]);
                const float x1 = __high2float(a2[j][cp]);
                a0[j] = fmaf(w0.x, x0, fmaf(w0.y, x1, a0[j]));
                a1[j] = fmaf(w1.x, x0, fmaf(w1.y, x1, a1[j]));
            }
        }
        {
            const float s0 = a0[0] + a0[1];
            const float q0 = fmaf(a0[0], a0[0], a0[1] * a0[1]);
            atomicAdd(&bsum[rep + o0], s0);
            atomicAdd(&bsum[rep + 24 + o0], q0);
            if (o1 < DOUT) {
                const float s1 = a1[0] + a1[1];
                const float q1 = fmaf(a1[0], a1[0], a1[1] * a1[1]);
                atomicAdd(&bsum[rep + o1], s1);
                atomicAdd(&bsum[rep + 24 + o1], q1);
            }
        }
#pragma unroll
        for (int j = 0; j < RPT; ++j)
            hp[j][op] = __floats2half2_rn(a0[j], (o1 < DOUT) ? a1[j] : 0.0f);
    }
#pragma unroll
    for (int j = 0; j < RPT; ++j) {
        __half2* wp = hout + (size_t)(rowbase + j * NTHR) * NPO;
#pragma unroll
        for (int op = 0; op < NPO; ++op) wp[op] = hp[j][op];
    }
    stats_finish<DOUT>(bsum, gslots, counter, g, bt, scsh_out, tid, bid);
}

// ---- layer 10: BN_9+tanh, linear 5->1, sigmoid -> out(f32) -----------------
__global__ void layer10(const __half2* __restrict__ hin, float* __restrict__ out,
                        const float* __restrict__ W, const float* __restrict__ b,
                        const float* __restrict__ scsh_prev) {
    __shared__ float lw[6], lsc[6], lsh[6];
    __shared__ float lb0;
    const int tid = threadIdx.x, bid = blockIdx.x;
    if (tid < 5) { lw[tid] = W[tid]; lsc[tid] = scsh_prev[2 * tid]; lsh[tid] = scsh_prev[2 * tid + 1]; }
    if (tid == 5) { lw[5] = 0.0f; lsc[5] = 0.0f; lsh[5] = 0.0f; }
    if (tid == 0) lb0 = b[0];
    __syncthreads();
    const int rowbase = bid * (NTHR * RPT) + tid;
#pragma unroll
    for (int j = 0; j < RPT; ++j) {
        const __half2* rp = hin + (size_t)(rowbase + j * NTHR) * 3;
        float a = lb0;
#pragma unroll
        for (int cp = 0; cp < 3; ++cp) {
            const __half2 hv = rp[cp];
            const float t0 = fast_tanh(fmaf(__low2float(hv), lsc[2 * cp], lsh[2 * cp]));
            const float t1 = fast_tanh(fmaf(__high2float(hv), lsc[2 * cp + 1], lsh[2 * cp + 1]));
            a = fmaf(lw[2 * cp], t0, fmaf(lw[2 * cp + 1], t1, a));
        }
        const float e = exp2f(a * -1.4426950408889634f);
        out[rowbase + j * NTHR] = __fdividef(1.0f, 1.0f + e);
    }
}

// zero gstats + counters each call (graph replays do not re-poison ws)
__global__ void init_ws(float* __restrict__ gstats, unsigned* __restrict__ counters) {
    const int i = threadIdx.x + blockIdx.x * blockDim.x;
    if (i < 10 * NSLOT * SLOTW) gstats[i] = 0.0f;
    if (i < 10 * 16) counters[i] = 0u;
}

extern "C" void kernel_launch(void* const* d_in, const int* in_sizes, int n_in,
                              void* d_out, int out_size, void* d_ws, size_t ws_size,
                              hipStream_t stream) {
    const float *W[11], *b[11], *g[10], *bt[10];
    const float* x = (const float*)d_in[0];
    int k = 1;
    for (int l = 0; l < 11; ++l) {
        W[l] = (const float*)d_in[k++];
        b[l] = (const float*)d_in[k++];
        if (l < 10) {
            g[l] = (const float*)d_in[k++];
            bt[l] = (const float*)d_in[k++];
        }
    }
    float* out = (float*)d_out;

    // ws layout (bytes):
    //   gstats   @ 0        : 10*64*48*4 = 122880
    //   counters @ 122880   : 10 counters, stride 16 uints (64B padded)
    //   scsh     @ 124160   : 10*64 floats (sc,sh pairs)
    //   hA       @ 131072   : 1M rows * <=5 dwords = 20971520
    //   hB       @ 21102592 : 1M rows * <=10 dwords = 41943040   (total ~63MB)
    char* ws = (char*)d_ws;
    float*    gstats   = (float*)ws;
    unsigned* counters = (unsigned*)(ws + 122880);
    float*    scsh     = (float*)(ws + 124160);
    __half2*  hA       = (__half2*)(ws + 131072);
    __half2*  hB       = (__half2*)(ws + 131072 + 20971520);

    auto GS = [&](int L) { return gstats + (size_t)L * NSLOT * SLOTW; };
    auto CT = [&](int L) { return counters + (size_t)L * 16; };
    auto SC = [&](int L) { return scsh + (size_t)L * 64; };

    init_ws<<<dim3(120), dim3(NTHR), 0, stream>>>(gstats, counters);
    layer0<<<dim3(NBLK), dim3(NTHR), 0, stream>>>(x, hA, W[0], b[0], g[0], bt[0],
                                                  SC(0), GS(0), CT(0));
    layer_mid<1><<<dim3(NBLK), dim3(NTHR), 0, stream>>>(hA, hB, W[1], b[1], g[1], bt[1],
                                                        SC(0), SC(1), GS(1), CT(1));
    layer_mid<2><<<dim3(NBLK), dim3(NTHR), 0, stream>>>(hB, hA, W[2], b[2], g[2], bt[2],
                                                        SC(1), SC(2), GS(2), CT(2));
    layer_mid<3><<<dim3(NBLK), dim3(NTHR), 0, stream>>>(hA, hB, W[3], b[3], g[3], bt[3],
                                                        SC(2), SC(3), GS(3), CT(3));
    layer_mid<4><<<dim3(NBLK), dim3(NTHR), 0, stream>>>(hB, hA, W[4], b[4], g[4], bt[4],
                                                        SC(3), SC(4), GS(4), CT(4));
    layer_mid<5><<<dim3(NBLK), dim3(NTHR), 0, stream>>>(hA, hB, W[5], b[5], g[5], bt[5],
                                                        SC(4), SC(5), GS(5), CT(5));
    layer_mid<6><<<dim3(NBLK), dim3(NTHR), 0, stream>>>(hB, hA, W[6], b[6], g[6], bt[6],
                                                        SC(5), SC(6), GS(6), CT(6));
    layer_mid<7><<<dim3(NBLK), dim3(NTHR), 0, stream>>>(hA, hB, W[7], b[7], g[7], bt[7],
                                                        SC(6), SC(7), GS(7), CT(7));
    layer_mid<8><<<dim3(NBLK), dim3(NTHR), 0, stream>>>(hB, hA, W[8], b[8], g[8], bt[8],
                                                        SC(7), SC(8), GS(8), CT(8));
    layer_mid<9><<<dim3(NBLK), dim3(NTHR), 0, stream>>>(hA, hB, W[9], b[9], g[9], bt[9],
                                                        SC(8), SC(9), GS(9), CT(9));
    layer10<<<dim3(NBLK), dim3(NTHR), 0, stream>>>(hB, out, W[10], b[10], SC(9));
}

// Round 6
// 1134.056 us; speedup vs baseline: 1.4345x; 1.0410x over previous
//
#include <hip/hip_runtime.h>
#include <hip/hip_fp16.h>

// ---------------------------------------------------------------------------
// Multi-kernel MLP: 12 graph-captured launches, kernel boundary = global sync.
// R6 vs R5 (1180us): fix access patterns.
//  * layer0 (269us, FETCH 518MB = 1.9x ideal, 2.0 TB/s): was per-lane
//    row-contiguous (lane stride 256B -> 64 sectors/instr + line eviction
//    across the 16-step col loop). Now: LDS-staged transpose. Block = 256
//    rows, two K-halves of 32 cols; cooperative coalesced float4 loads ->
//    LDS [256][36] (stride 36 floats: 16B-aligned, b128 reads at the 8-phase
//    minimum) -> thread-per-row reads from LDS.
//  * intermediates: column-PLANES (SoA). Plane cp = __half2[1M]; all h
//    loads/stores are 4B/lane lane-consecutive = 256B/wave coalesced
//    (was 20-40B lane stride, 4B used per sector).
// Stats machinery unchanged from R5 (it worked): LDS replicas -> 64 padded
// global slots -> last-block (acq_rel counter) writes scale/shift for the
// next kernel.
// ---------------------------------------------------------------------------

#define NTHR 256
#define BATCHN 1048576
#define L0BLK 4096     // layer0: 1 row/thread, 256 rows/block
#define MIDBLK 2048    // mid layers: 2 rows/thread
#define MIDRPT 2
#define NREP 32        // LDS stat replicas (stride 49 odd -> bank bijection)
#define SSTR 49
#define NSLOT 64       // global stat slots
#define SLOTW 48       // floats per slot: [0..23]=sum, [24..47]=sumsq

static_assert(L0BLK * NTHR == BATCHN, "layer0 row coverage");
static_assert(MIDBLK * NTHR * MIDRPT == BATCHN, "mid row coverage");

static constexpr int D_[12] = {64, 4, 20, 10, 10, 10, 10, 10, 5, 5, 5, 1};

__device__ __forceinline__ float fast_tanh(float x) {
    const float e = exp2f(x * 2.8853900817779268f);
    return 1.0f - __fdividef(2.0f, e + 1.0f);
}

// ---- per-layer stats finalization ------------------------------------------
template <int DOUT, int TOTBLK>
__device__ __forceinline__ void stats_finish(float* bsum, float* __restrict__ gslots,
                                             unsigned* __restrict__ counter,
                                             const float* __restrict__ g,
                                             const float* __restrict__ bt,
                                             float* __restrict__ scsh_out,
                                             int tid, int bid) {
    __syncthreads();   // all LDS stat atomics done
    if (tid < 2 * DOUT) {
        const int idx = (tid < DOUT) ? tid : (24 + (tid - DOUT));
        float v = 0.0f;
        for (int r = 0; r < NREP; ++r) v += bsum[r * SSTR + idx];
        atomicAdd(&gslots[(bid & (NSLOT - 1)) * SLOTW + idx], v);   // device scope
    }
    __syncthreads();   // block's slot adds issued before counter bump
    __shared__ int lastflag;
    if (tid == 0) {
        const unsigned old = __hip_atomic_fetch_add(counter, 1u, __ATOMIC_ACQ_REL,
                                                    __HIP_MEMORY_SCOPE_AGENT);
        lastflag = (old == (unsigned)(TOTBLK - 1));
    }
    __syncthreads();
    if (lastflag && tid < DOUT) {
        float s = 0.0f, s2 = 0.0f;
        for (int q = 0; q < NSLOT; ++q) {
            s  += __hip_atomic_load(&gslots[q * SLOTW + tid],
                                    __ATOMIC_RELAXED, __HIP_MEMORY_SCOPE_AGENT);
            s2 += __hip_atomic_load(&gslots[q * SLOTW + 24 + tid],
                                    __ATOMIC_RELAXED, __HIP_MEMORY_SCOPE_AGENT);
        }
        constexpr float inv = 1.0f / (float)BATCHN;
        const float m = s * inv;
        const float var = fmaxf(s2 * inv - m * m, 0.0f);
        const float sc = g[tid] * rsqrtf(var + 1e-5f);
        scsh_out[2 * tid]     = sc;                 // visible at kernel boundary
        scsh_out[2 * tid + 1] = bt[tid] - m * sc;
    }
}

// ---- layer 0: x(64) -> h0(4 features, 2 planes), LDS-staged transpose ------
__global__ void __launch_bounds__(NTHR) layer0(
        const float* __restrict__ x, __half2* __restrict__ hout,
        const float* __restrict__ W, const float* __restrict__ b,
        const float* __restrict__ g, const float* __restrict__ bt,
        float* __restrict__ scsh_out, float* __restrict__ gslots,
        unsigned* __restrict__ counter) {
    __shared__ __align__(16) float lw0[256];     // [4][64]
    __shared__ float lb[4];
    __shared__ float bsum[NREP * SSTR];
    __shared__ __align__(16) float xs[256 * 36]; // 256 rows x 32 cols, stride 36
    const int tid = threadIdx.x, bid = blockIdx.x;
    lw0[tid] = W[tid];
    if (tid < 4) lb[tid] = b[tid];
    for (int i = tid; i < NREP * SSTR; i += NTHR) bsum[i] = 0.0f;
    __syncthreads();

    const int row0 = bid * 256;
    float acc[4] = {lb[0], lb[1], lb[2], lb[3]};

#pragma unroll
    for (int h = 0; h < 2; ++h) {
        float4 v[8];
#pragma unroll
        for (int j = 0; j < 8; ++j) {
            const int i4 = tid + j * NTHR;          // 0..2047
            const int r = i4 >> 3, c4 = (i4 & 7) * 4;
            v[j] = *(const float4*)(x + (size_t)(row0 + r) * 64 + h * 32 + c4);
        }
        if (h) __syncthreads();                     // prev-half reads complete
#pragma unroll
        for (int j = 0; j < 8; ++j) {
            const int i4 = tid + j * NTHR;
            const int r = i4 >> 3, c4 = (i4 & 7) * 4;
            *(float4*)&xs[r * 36 + c4] = v[j];
        }
        __syncthreads();
#pragma unroll
        for (int c4 = 0; c4 < 8; ++c4) {
            const float4 xv = *(const float4*)&xs[tid * 36 + c4 * 4];
#pragma unroll
            for (int o = 0; o < 4; ++o) {
                const float4 w = *(const float4*)&lw0[o * 64 + h * 32 + c4 * 4];
                acc[o] = fmaf(w.x, xv.x, fmaf(w.y, xv.y,
                          fmaf(w.z, xv.z, fmaf(w.w, xv.w, acc[o]))));
            }
        }
    }

    const int rep = (tid & 31) * SSTR;
#pragma unroll
    for (int d = 0; d < 4; ++d) {
        atomicAdd(&bsum[rep + d], acc[d]);
        atomicAdd(&bsum[rep + 24 + d], acc[d] * acc[d]);
    }
    const int row = row0 + tid;
    hout[row]          = __floats2half2_rn(acc[0], acc[1]);   // plane 0
    hout[BATCHN + row] = __floats2half2_rn(acc[2], acc[3]);   // plane 1
    stats_finish<4, L0BLK>(bsum, gslots, counter, g, bt, scsh_out, tid, bid);
}

// ---- layers 1..9: BN_{L-1}+tanh fused in, linear, emit h_L planes ----------
template <int L>
__global__ void __launch_bounds__(NTHR) layer_mid(
        const __half2* __restrict__ hin, __half2* __restrict__ hout,
        const float* __restrict__ W, const float* __restrict__ b,
        const float* __restrict__ g, const float* __restrict__ bt,
        const float* __restrict__ scsh_prev, float* __restrict__ scsh_out,
        float* __restrict__ gslots, unsigned* __restrict__ counter) {
    constexpr int DIN = D_[L], DOUT = D_[L + 1];
    constexpr int NPI = (DIN + 1) / 2, NPO = (DOUT + 1) / 2;
    __shared__ float2 lw[DOUT * NPI];
    __shared__ float lb[DOUT], lsc[DIN], lsh[DIN];
    __shared__ float bsum[NREP * SSTR];
    const int tid = threadIdx.x, bid = blockIdx.x;
    for (int i = tid; i < DOUT * NPI; i += NTHR) {
        const int o = i / NPI, cp = i - o * NPI;
        const float w0 = W[o * DIN + 2 * cp];
        const float w1 = (2 * cp + 1 < DIN) ? W[o * DIN + 2 * cp + 1] : 0.0f;
        lw[i] = make_float2(w0, w1);
    }
    if (tid < DOUT) lb[tid] = b[tid];
    if (tid < DIN) { lsc[tid] = scsh_prev[2 * tid]; lsh[tid] = scsh_prev[2 * tid + 1]; }
    for (int i = tid; i < NREP * SSTR; i += NTHR) bsum[i] = 0.0f;
    __syncthreads();

    const int rowbase = bid * (NTHR * MIDRPT) + tid;

    // load planes, apply BN+tanh, repack to f16 pairs
    __half2 a2[MIDRPT][NPI];
#pragma unroll
    for (int j = 0; j < MIDRPT; ++j) {
        const int row = rowbase + j * NTHR;
#pragma unroll
        for (int cp = 0; cp < NPI; ++cp) {
            const __half2 hv = hin[(size_t)cp * BATCHN + row];
            const float t0 = fast_tanh(fmaf(__low2float(hv), lsc[2 * cp], lsh[2 * cp]));
            const float t1 = (2 * cp + 1 < DIN)
                ? fast_tanh(fmaf(__high2float(hv), lsc[2 * cp + 1], lsh[2 * cp + 1]))
                : 0.0f;
            a2[j][cp] = __floats2half2_rn(t0, t1);
        }
    }

    const int rep = (tid & 31) * SSTR;
#pragma unroll
    for (int op = 0; op < NPO; ++op) {
        const int o0 = 2 * op, o1 = 2 * op + 1;
        float a0[MIDRPT], a1[MIDRPT];
#pragma unroll
        for (int j = 0; j < MIDRPT; ++j) {
            a0[j] = lb[o0];
            a1[j] = (o1 < DOUT) ? lb[o1] : 0.0f;
        }
#pragma unroll
        for (int cp = 0; cp < NPI; ++cp) {
            const float2 w0 = lw[o0 * NPI + cp];
            const float2 w1 = (o1 < DOUT) ? lw[o1 * NPI + cp] : make_float2(0.0f, 0.0f);
#pragma unroll
            for (int j = 0; j < MIDRPT; ++j) {
                const float x0 = __low2float(a2[j][cp]);
                const float x1 = __high2float(a2[j][cp]);
                a0[j] = fmaf(w0.x, x0, fmaf(w0.y, x1, a0[j]));
                a1[j] = fmaf(w1.x, x0, fmaf(w1.y, x1, a1[j]));
            }
        }
        {
            const float s0 = a0[0] + a0[1];
            const float q0 = fmaf(a0[0], a0[0], a0[1] * a0[1]);
            atomicAdd(&bsum[rep + o0], s0);
            atomicAdd(&bsum[rep + 24 + o0], q0);
            if (o1 < DOUT) {
                const float s1 = a1[0] + a1[1];
                const float q1 = fmaf(a1[0], a1[0], a1[1] * a1[1]);
                atomicAdd(&bsum[rep + o1], s1);
                atomicAdd(&bsum[rep + 24 + o1], q1);
            }
        }
#pragma unroll
        for (int j = 0; j < MIDRPT; ++j)
            hout[(size_t)op * BATCHN + rowbase + j * NTHR] =
                __floats2half2_rn(a0[j], (o1 < DOUT) ? a1[j] : 0.0f);
    }
    stats_finish<DOUT, MIDBLK>(bsum, gslots, counter, g, bt, scsh_out, tid, bid);
}

// ---- layer 10: BN_9+tanh, linear 5->1, sigmoid -> out(f32) -----------------
__global__ void __launch_bounds__(NTHR) layer10(
        const __half2* __restrict__ hin, float* __restrict__ out,
        const float* __restrict__ W, const float* __restrict__ b,
        const float* __restrict__ scsh_prev) {
    __shared__ float lw[6], lsc[6], lsh[6];
    __shared__ float lb0;
    const int tid = threadIdx.x, bid = blockIdx.x;
    if (tid < 5) { lw[tid] = W[tid]; lsc[tid] = scsh_prev[2 * tid]; lsh[tid] = scsh_prev[2 * tid + 1]; }
    if (tid == 5) { lw[5] = 0.0f; lsc[5] = 0.0f; lsh[5] = 0.0f; }
    if (tid == 0) lb0 = b[0];
    __syncthreads();
    const int rowbase = bid * (NTHR * MIDRPT) + tid;
#pragma unroll
    for (int j = 0; j < MIDRPT; ++j) {
        const int row = rowbase + j * NTHR;
        float a = lb0;
#pragma unroll
        for (int cp = 0; cp < 3; ++cp) {
            const __half2 hv = hin[(size_t)cp * BATCHN + row];
            const float t0 = fast_tanh(fmaf(__low2float(hv), lsc[2 * cp], lsh[2 * cp]));
            const float t1 = fast_tanh(fmaf(__high2float(hv), lsc[2 * cp + 1], lsh[2 * cp + 1]));
            a = fmaf(lw[2 * cp], t0, fmaf(lw[2 * cp + 1], t1, a));
        }
        const float e = exp2f(a * -1.4426950408889634f);
        out[row] = __fdividef(1.0f, 1.0f + e);
    }
}

// zero gstats + counters each call (graph replays do not re-poison ws)
__global__ void init_ws(float* __restrict__ gstats, unsigned* __restrict__ counters) {
    const int i = threadIdx.x + blockIdx.x * blockDim.x;
    if (i < 10 * NSLOT * SLOTW) gstats[i] = 0.0f;
    if (i < 10 * 16) counters[i] = 0u;
}

extern "C" void kernel_launch(void* const* d_in, const int* in_sizes, int n_in,
                              void* d_out, int out_size, void* d_ws, size_t ws_size,
                              hipStream_t stream) {
    const float *W[11], *b[11], *g[10], *bt[10];
    const float* x = (const float*)d_in[0];
    int k = 1;
    for (int l = 0; l < 11; ++l) {
        W[l] = (const float*)d_in[k++];
        b[l] = (const float*)d_in[k++];
        if (l < 10) {
            g[l] = (const float*)d_in[k++];
            bt[l] = (const float*)d_in[k++];
        }
    }
    float* out = (float*)d_out;

    // ws layout (bytes):
    //   gstats   @ 0        : 10*64*48*4 = 122880
    //   counters @ 122880   : 10 counters, stride 16 uints
    //   scsh     @ 124160   : 10*64 floats
    //   hA       @ 131072   : 5 planes x 4MB = 20971520  (h0:2, h2/h4/h6:5, h8:3)
    //   hB       @ 21102592 : 10 planes x 4MB = 41943040 (h1:10, h3/h5/h7:5, h9:3)
    char* ws = (char*)d_ws;
    float*    gstats   = (float*)ws;
    unsigned* counters = (unsigned*)(ws + 122880);
    float*    scsh     = (float*)(ws + 124160);
    __half2*  hA       = (__half2*)(ws + 131072);
    __half2*  hB       = (__half2*)(ws + 131072 + 20971520);

    auto GS = [&](int L) { return gstats + (size_t)L * NSLOT * SLOTW; };
    auto CT = [&](int L) { return counters + (size_t)L * 16; };
    auto SC = [&](int L) { return scsh + (size_t)L * 64; };

    init_ws<<<dim3(120), dim3(NTHR), 0, stream>>>(gstats, counters);
    layer0<<<dim3(L0BLK), dim3(NTHR), 0, stream>>>(x, hA, W[0], b[0], g[0], bt[0],
                                                   SC(0), GS(0), CT(0));
    layer_mid<1><<<dim3(MIDBLK), dim3(NTHR), 0, stream>>>(hA, hB, W[1], b[1], g[1], bt[1],
                                                          SC(0), SC(1), GS(1), CT(1));
    layer_mid<2><<<dim3(MIDBLK), dim3(NTHR), 0, stream>>>(hB, hA, W[2], b[2], g[2], bt[2],
                                                          SC(1), SC(2), GS(2), CT(2));
    layer_mid<3><<<dim3(MIDBLK), dim3(NTHR), 0, stream>>>(hA, hB, W[3], b[3], g[3], bt[3],
                                                          SC(2), SC(3), GS(3), CT(3));
    layer_mid<4><<<dim3(MIDBLK), dim3(NTHR), 0, stream>>>(hB, hA, W[4], b[4], g[4], bt[4],
                                                          SC(3), SC(4), GS(4), CT(4));
    layer_mid<5><<<dim3(MIDBLK), dim3(NTHR), 0, stream>>>(hA, hB, W[5], b[5], g[5], bt[5],
                                                          SC(4), SC(5), GS(5), CT(5));
    layer_mid<6><<<dim3(MIDBLK), dim3(NTHR), 0, stream>>>(hB, hA, W[6], b[6], g[6], bt[6],
                                                          SC(5), SC(6), GS(6), CT(6));
    layer_mid<7><<<dim3(MIDBLK), dim3(NTHR), 0, stream>>>(hA, hB, W[7], b[7], g[7], bt[7],
                                                          SC(6), SC(7), GS(7), CT(7));
    layer_mid<8><<<dim3(MIDBLK), dim3(NTHR), 0, stream>>>(hB, hA, W[8], b[8], g[8], bt[8],
                                                          SC(7), SC(8), GS(8), CT(8));
    layer_mid<9><<<dim3(MIDBLK), dim3(NTHR), 0, stream>>>(hA, hB, W[9], b[9], g[9], bt[9],
                                                          SC(8), SC(9), GS(9), CT(9));
    layer10<<<dim3(MIDBLK), dim3(NTHR), 0, stream>>>(hB, out, W[10], b[10], SC(9));
}

// Round 7
// 753.124 us; speedup vs baseline: 2.1600x; 1.5058x over previous
//
#include <hip/hip_runtime.h>
#include <hip/hip_fp16.h>

// ---------------------------------------------------------------------------
// Multi-kernel MLP: 12 graph-captured launches, kernel boundary = global sync.
// R7 vs R6 (1134us):
//  * REMOVED the per-layer device-scope done-counter (2048 serialized acq_rel
//    RMWs on one line ~ 60us/kernel, the dominant constant since R1). Each
//    consumer kernel now reduces the producer's 64 padded stat slots in its
//    prologue (12KB L2-broadcast reads over 256 threads); the kernel boundary
//    provides visibility. No counter, no last-block, no scsh.
//  * layer0 rebuilt: 16 lanes per row, float4/lane -> each wave reads 1KB
//    fully contiguous; per-output partials reduced with 4x __shfl_xor
//    butterfly; weights in 16 VGPRs; LDS = 8KB (hs gather + bsum replicas)
//    -> high occupancy, no register staging (R6's 265MB write mystery).
//  * mid layers: R6's coalesced column-planes kept verbatim.
// ---------------------------------------------------------------------------

#define NTHR 256
#define BATCHN 1048576
#define L0BLK 2048     // layer0: 2 tiles of 256 rows per block
#define L0TPB 2
#define MIDBLK 2048    // mid layers: 2 rows/thread
#define MIDRPT 2
#define NREP 32        // LDS stat replicas (stride 49 odd -> bank bijection)
#define SSTR 49
#define NSLOT 64       // global stat slots
#define SLOTW 48       // floats per slot: [0..23]=sum, [24..47]=sumsq

static_assert(L0BLK * L0TPB * NTHR == BATCHN, "layer0 row coverage");
static_assert(MIDBLK * NTHR * MIDRPT == BATCHN, "mid row coverage");

static constexpr int D_[12] = {64, 4, 20, 10, 10, 10, 10, 10, 5, 5, 5, 1};

__device__ __forceinline__ float fast_tanh(float x) {
    const float e = exp2f(x * 2.8853900817779268f);
    return 1.0f - __fdividef(2.0f, e + 1.0f);
}

// ---- block-end stats deposit: LDS replicas -> one global atomic per block --
template <int DOUT>
__device__ __forceinline__ void stats_deposit(float* bsum, float* __restrict__ gslots,
                                              int tid, int bid) {
    __syncthreads();   // all LDS stat atomics done
    if (tid < 2 * DOUT) {
        const int idx = (tid < DOUT) ? tid : (24 + (tid - DOUT));
        float v = 0.0f;
        for (int r = 0; r < NREP; ++r) v += bsum[r * SSTR + idx];
        atomicAdd(&gslots[(bid & (NSLOT - 1)) * SLOTW + idx], v);   // device scope
    }
}

// ---- prologue: reduce previous layer's slots -> lsc/lsh (per block) --------
template <int DIN>
__device__ __forceinline__ void slots_to_scsh(const float* __restrict__ gsPrev,
                                              const float* __restrict__ gPrev,
                                              const float* __restrict__ btPrev,
                                              float* red, float* lsc, float* lsh,
                                              int tid) {
    // red[0..2*DIN) zeroed by caller before a __syncthreads()
    for (int i = tid; i < NSLOT * 2 * DIN; i += NTHR) {
        const int q = i / (2 * DIN), f = i - q * (2 * DIN);
        const int idx = (f < DIN) ? f : (24 + (f - DIN));
        atomicAdd(&red[f], gsPrev[q * SLOTW + idx]);
    }
    __syncthreads();
    if (tid < DIN) {
        constexpr float inv = 1.0f / (float)BATCHN;
        const float m = red[tid] * inv;
        const float var = fmaxf(red[DIN + tid] * inv - m * m, 0.0f);
        const float sc = gPrev[tid] * rsqrtf(var + 1e-5f);
        lsc[tid] = sc;
        lsh[tid] = btPrev[tid] - m * sc;
    }
    __syncthreads();
}

// ---- layer 0: x(64) -> h0 (4 features = 2 planes), shuffle-reduce ----------
__global__ void __launch_bounds__(NTHR) layer0(
        const float* __restrict__ x, __half2* __restrict__ hout,
        const float* __restrict__ W, const float* __restrict__ b,
        float* __restrict__ gslots) {
    __shared__ float bsum[NREP * SSTR];
    __shared__ __half2 hs[2][256];
    const int tid = threadIdx.x, bid = blockIdx.x;
    for (int i = tid; i < NREP * SSTR; i += NTHR) bsum[i] = 0.0f;

    // per-thread weight fragment: 4 outputs x 4 cols at c0 = (tid&15)*4
    const int c0 = (tid & 15) * 4;
    float w[4][4];
    float bb[4];
#pragma unroll
    for (int o = 0; o < 4; ++o) {
        const float4 wv = *(const float4*)(W + o * 64 + c0);
        w[o][0] = wv.x; w[o][1] = wv.y; w[o][2] = wv.z; w[o][3] = wv.w;
        bb[o] = b[o];
    }
    float sl[4] = {0.f, 0.f, 0.f, 0.f}, ql[4] = {0.f, 0.f, 0.f, 0.f};
    __syncthreads();   // bsum zero done

#pragma unroll
    for (int t = 0; t < L0TPB; ++t) {
        const int tilebase = (bid * L0TPB + t) * 256;
#pragma unroll
        for (int p = 0; p < 16; ++p) {
            const int row = tilebase + p * 16 + (tid >> 4);
            const float4 xv = *(const float4*)(x + (size_t)row * 64 + c0);
            float par[4];
#pragma unroll
            for (int o = 0; o < 4; ++o)
                par[o] = fmaf(w[o][0], xv.x, fmaf(w[o][1], xv.y,
                          fmaf(w[o][2], xv.z, w[o][3] * xv.w)));
            // butterfly within each 16-lane group -> all lanes hold row sums
#pragma unroll
            for (int mask = 1; mask < 16; mask <<= 1)
#pragma unroll
                for (int o = 0; o < 4; ++o)
                    par[o] += __shfl_xor(par[o], mask, 64);
            float hv[4];
#pragma unroll
            for (int o = 0; o < 4; ++o) {
                hv[o] = par[o] + bb[o];
                sl[o] += hv[o];
                ql[o] = fmaf(hv[o], hv[o], ql[o]);
            }
            if ((tid & 15) == 0) {
                const int rp = p * 16 + (tid >> 4);
                hs[0][rp] = __floats2half2_rn(hv[0], hv[1]);
                hs[1][rp] = __floats2half2_rn(hv[2], hv[3]);
            }
        }
        __syncthreads();
        hout[tilebase + tid]          = hs[0][tid];
        hout[BATCHN + tilebase + tid] = hs[1][tid];
        __syncthreads();   // before next tile reuses hs
    }

    // stats: every lane accumulated 16x-replicated sums -> scale by 1/16
    const int rep = (tid & 31) * SSTR;
#pragma unroll
    for (int o = 0; o < 4; ++o) {
        atomicAdd(&bsum[rep + o],      sl[o] * 0.0625f);
        atomicAdd(&bsum[rep + 24 + o], ql[o] * 0.0625f);
    }
    stats_deposit<4>(bsum, gslots, tid, bid);
}

// ---- layers 1..9: prologue BN params, BN+tanh fused, linear, emit planes ---
template <int L>
__global__ void __launch_bounds__(NTHR) layer_mid(
        const __half2* __restrict__ hin, __half2* __restrict__ hout,
        const float* __restrict__ W, const float* __restrict__ b,
        const float* __restrict__ gPrev, const float* __restrict__ btPrev,
        const float* __restrict__ gsPrev, float* __restrict__ gsOut) {
    constexpr int DIN = D_[L], DOUT = D_[L + 1];
    constexpr int NPI = (DIN + 1) / 2, NPO = (DOUT + 1) / 2;
    __shared__ float2 lw[DOUT * NPI];
    __shared__ float lb[DOUT], lsc[DIN], lsh[DIN];
    __shared__ float red[2 * DIN];
    __shared__ float bsum[NREP * SSTR];
    const int tid = threadIdx.x, bid = blockIdx.x;
    for (int i = tid; i < DOUT * NPI; i += NTHR) {
        const int o = i / NPI, cp = i - o * NPI;
        const float w0 = W[o * DIN + 2 * cp];
        const float w1 = (2 * cp + 1 < DIN) ? W[o * DIN + 2 * cp + 1] : 0.0f;
        lw[i] = make_float2(w0, w1);
    }
    if (tid < DOUT) lb[tid] = b[tid];
    if (tid < 2 * DIN) red[tid] = 0.0f;
    for (int i = tid; i < NREP * SSTR; i += NTHR) bsum[i] = 0.0f;
    __syncthreads();
    slots_to_scsh<DIN>(gsPrev, gPrev, btPrev, red, lsc, lsh, tid);

    const int rowbase = bid * (NTHR * MIDRPT) + tid;

    // load planes, apply BN+tanh, repack to f16 pairs
    __half2 a2[MIDRPT][NPI];
#pragma unroll
    for (int j = 0; j < MIDRPT; ++j) {
        const int row = rowbase + j * NTHR;
#pragma unroll
        for (int cp = 0; cp < NPI; ++cp) {
            const __half2 hv = hin[(size_t)cp * BATCHN + row];
            const float t0 = fast_tanh(fmaf(__low2float(hv), lsc[2 * cp], lsh[2 * cp]));
            const float t1 = (2 * cp + 1 < DIN)
                ? fast_tanh(fmaf(__high2float(hv), lsc[2 * cp + 1], lsh[2 * cp + 1]))
                : 0.0f;
            a2[j][cp] = __floats2half2_rn(t0, t1);
        }
    }

    const int rep = (tid & 31) * SSTR;
#pragma unroll
    for (int op = 0; op < NPO; ++op) {
        const int o0 = 2 * op, o1 = 2 * op + 1;
        float a0[MIDRPT], a1[MIDRPT];
#pragma unroll
        for (int j = 0; j < MIDRPT; ++j) {
            a0[j] = lb[o0];
            a1[j] = (o1 < DOUT) ? lb[o1] : 0.0f;
        }
#pragma unroll
        for (int cp = 0; cp < NPI; ++cp) {
            const float2 w0 = lw[o0 * NPI + cp];
            const float2 w1 = (o1 < DOUT) ? lw[o1 * NPI + cp] : make_float2(0.0f, 0.0f);
#pragma unroll
            for (int j = 0; j < MIDRPT; ++j) {
                const float x0 = __low2float(a2[j][cp]);
                const float x1 = __high2float(a2[j][cp]);
                a0[j] = fmaf(w0.x, x0, fmaf(w0.y, x1, a0[j]));
                a1[j] = fmaf(w1.x, x0, fmaf(w1.y, x1, a1[j]));
            }
        }
        {
            const float s0 = a0[0] + a0[1];
            const float q0 = fmaf(a0[0], a0[0], a0[1] * a0[1]);
            atomicAdd(&bsum[rep + o0], s0);
            atomicAdd(&bsum[rep + 24 + o0], q0);
            if (o1 < DOUT) {
                const float s1 = a1[0] + a1[1];
                const float q1 = fmaf(a1[0], a1[0], a1[1] * a1[1]);
                atomicAdd(&bsum[rep + o1], s1);
                atomicAdd(&bsum[rep + 24 + o1], q1);
            }
        }
#pragma unroll
        for (int j = 0; j < MIDRPT; ++j)
            hout[(size_t)op * BATCHN + rowbase + j * NTHR] =
                __floats2half2_rn(a0[j], (o1 < DOUT) ? a1[j] : 0.0f);
    }
    stats_deposit<DOUT>(bsum, gsOut, tid, bid);
}

// ---- layer 10: prologue BN_9, tanh, linear 5->1, sigmoid -> out(f32) -------
__global__ void __launch_bounds__(NTHR) layer10(
        const __half2* __restrict__ hin, float* __restrict__ out,
        const float* __restrict__ W, const float* __restrict__ b,
        const float* __restrict__ gPrev, const float* __restrict__ btPrev,
        const float* __restrict__ gsPrev) {
    __shared__ float lw[6], lsc[6], lsh[6];
    __shared__ float red[10];
    __shared__ float lb0;
    const int tid = threadIdx.x, bid = blockIdx.x;
    if (tid < 5) lw[tid] = W[tid];
    if (tid == 5) { lw[5] = 0.0f; lsc[5] = 0.0f; lsh[5] = 0.0f; }
    if (tid == 0) lb0 = b[0];
    if (tid < 10) red[tid] = 0.0f;
    __syncthreads();
    slots_to_scsh<5>(gsPrev, gPrev, btPrev, red, lsc, lsh, tid);

    const int rowbase = bid * (NTHR * MIDRPT) + tid;
#pragma unroll
    for (int j = 0; j < MIDRPT; ++j) {
        const int row = rowbase + j * NTHR;
        float a = lb0;
#pragma unroll
        for (int cp = 0; cp < 3; ++cp) {
            const __half2 hv = hin[(size_t)cp * BATCHN + row];
            const float t0 = fast_tanh(fmaf(__low2float(hv), lsc[2 * cp], lsh[2 * cp]));
            const float t1 = fast_tanh(fmaf(__high2float(hv), lsc[2 * cp + 1], lsh[2 * cp + 1]));
            a = fmaf(lw[2 * cp], t0, fmaf(lw[2 * cp + 1], t1, a));
        }
        const float e = exp2f(a * -1.4426950408889634f);
        out[row] = __fdividef(1.0f, 1.0f + e);
    }
}

// zero gslots each call (graph replays do not re-poison ws)
__global__ void init_ws(float* __restrict__ gstats) {
    const int i = threadIdx.x + blockIdx.x * blockDim.x;
    if (i < 10 * NSLOT * SLOTW) gstats[i] = 0.0f;
}

extern "C" void kernel_launch(void* const* d_in, const int* in_sizes, int n_in,
                              void* d_out, int out_size, void* d_ws, size_t ws_size,
                              hipStream_t stream) {
    const float *W[11], *b[11], *g[10], *bt[10];
    const float* x = (const float*)d_in[0];
    int k = 1;
    for (int l = 0; l < 11; ++l) {
        W[l] = (const float*)d_in[k++];
        b[l] = (const float*)d_in[k++];
        if (l < 10) {
            g[l] = (const float*)d_in[k++];
            bt[l] = (const float*)d_in[k++];
        }
    }
    float* out = (float*)d_out;

    // ws layout (bytes):
    //   gstats @ 0        : 10*64*48*4 = 122880
    //   hA     @ 131072   : 5 planes x 4MB  (h0:2, h2/h4/h6:5, h8:3)
    //   hB     @ 21102592 : 10 planes x 4MB (h1:10, h3/h5/h7:5, h9:3)
    char* ws = (char*)d_ws;
    float*   gstats = (float*)ws;
    __half2* hA     = (__half2*)(ws + 131072);
    __half2* hB     = (__half2*)(ws + 131072 + 20971520);

    auto GS = [&](int L) { return gstats + (size_t)L * NSLOT * SLOTW; };

    init_ws<<<dim3(120), dim3(NTHR), 0, stream>>>(gstats);
    layer0<<<dim3(L0BLK), dim3(NTHR), 0, stream>>>(x, hA, W[0], b[0], GS(0));
    layer_mid<1><<<dim3(MIDBLK), dim3(NTHR), 0, stream>>>(hA, hB, W[1], b[1],
                                                          g[0], bt[0], GS(0), GS(1));
    layer_mid<2><<<dim3(MIDBLK), dim3(NTHR), 0, stream>>>(hB, hA, W[2], b[2],
                                                          g[1], bt[1], GS(1), GS(2));
    layer_mid<3><<<dim3(MIDBLK), dim3(NTHR), 0, stream>>>(hA, hB, W[3], b[3],
                                                          g[2], bt[2], GS(2), GS(3));
    layer_mid<4><<<dim3(MIDBLK), dim3(NTHR), 0, stream>>>(hB, hA, W[4], b[4],
                                                          g[3], bt[3], GS(3), GS(4));
    layer_mid<5><<<dim3(MIDBLK), dim3(NTHR), 0, stream>>>(hA, hB, W[5], b[5],
                                                          g[4], bt[4], GS(4), GS(5));
    layer_mid<6><<<dim3(MIDBLK), dim3(NTHR), 0, stream>>>(hB, hA, W[6], b[6],
                                                          g[5], bt[5], GS(5), GS(6));
    layer_mid<7><<<dim3(MIDBLK), dim3(NTHR), 0, stream>>>(hA, hB, W[7], b[7],
                                                          g[6], bt[6], GS(6), GS(7));
    layer_mid<8><<<dim3(MIDBLK), dim3(NTHR), 0, stream>>>(hB, hA, W[8], b[8],
                                                          g[7], bt[7], GS(7), GS(8));
    layer_mid<9><<<dim3(MIDBLK), dim3(NTHR), 0, stream>>>(hA, hB, W[9], b[9],
                                                          g[8], bt[8], GS(8), GS(9));
    layer10<<<dim3(MIDBLK), dim3(NTHR), 0, stream>>>(hB, out, W[10], b[10],
                                                     g[9], bt[9], GS(9));
}

// Round 8
// 438.934 us; speedup vs baseline: 3.7061x; 1.7158x over previous
//
#include <hip/hip_runtime.h>
#include <hip/hip_fp16.h>

// ---------------------------------------------------------------------------
// Multi-kernel MLP: 12 graph-captured launches, kernel boundary = global sync.
// R8 vs R7 (753us): mid-kernels averaged ~55us vs ~10us roofline; layer0
// ~140us. Changes:
//  * ALL plane I/O vectorized: each thread owns 4 consecutive rows, so every
//    plane load/store is one float4 (= 4 __half2) -> 16B/lane, 1KB/wave,
//    4-deep ILP. Grid 1024 blocks (4 blocks/CU).
//  * layer0: 4 lanes/row x 16 cols each (weights hoisted to 64 VGPRs),
//    2 shuffle levels per row-group (0.5 shfl/row vs R7's 4/row, which was
//    DS-pipe bound). Reads tile 4KB windows fully; writes by group leaders.
//  * stats machinery unchanged from R7 (slots + consumer-prologue reduce).
// ---------------------------------------------------------------------------

#define NTHR 256
#define BATCHN 1048576
#define L0BLK 1024     // layer0: 1024 rows/block
#define MIDBLK 1024    // mid layers: 4 rows/thread
#define NREP 32        // LDS stat replicas (stride 49 odd -> bank bijection)
#define SSTR 49
#define NSLOT 64       // global stat slots
#define SLOTW 48       // floats per slot: [0..23]=sum, [24..47]=sumsq

static_assert(L0BLK * 1024 == BATCHN, "layer0 row coverage");
static_assert(MIDBLK * NTHR * 4 == BATCHN, "mid row coverage");

static constexpr int D_[12] = {64, 4, 20, 10, 10, 10, 10, 10, 5, 5, 5, 1};

__device__ __forceinline__ float fast_tanh(float x) {
    const float e = exp2f(x * 2.8853900817779268f);
    return 1.0f - __fdividef(2.0f, e + 1.0f);
}

// ---- block-end stats deposit: LDS replicas -> one global atomic per block --
template <int DOUT>
__device__ __forceinline__ void stats_deposit(float* bsum, float* __restrict__ gslots,
                                              int tid, int bid) {
    __syncthreads();   // all LDS stat atomics done
    if (tid < 2 * DOUT) {
        const int idx = (tid < DOUT) ? tid : (24 + (tid - DOUT));
        float v = 0.0f;
        for (int r = 0; r < NREP; ++r) v += bsum[r * SSTR + idx];
        atomicAdd(&gslots[(bid & (NSLOT - 1)) * SLOTW + idx], v);   // device scope
    }
}

// ---- prologue: reduce previous layer's slots -> lsc/lsh (per block) --------
template <int DIN>
__device__ __forceinline__ void slots_to_scsh(const float* __restrict__ gsPrev,
                                              const float* __restrict__ gPrev,
                                              const float* __restrict__ btPrev,
                                              float* red, float* lsc, float* lsh,
                                              int tid) {
    for (int i = tid; i < NSLOT * 2 * DIN; i += NTHR) {
        const int q = i / (2 * DIN), f = i - q * (2 * DIN);
        const int idx = (f < DIN) ? f : (24 + (f - DIN));
        atomicAdd(&red[f], gsPrev[q * SLOTW + idx]);
    }
    __syncthreads();
    if (tid < DIN) {
        constexpr float inv = 1.0f / (float)BATCHN;
        const float m = red[tid] * inv;
        const float var = fmaxf(red[DIN + tid] * inv - m * m, 0.0f);
        const float sc = gPrev[tid] * rsqrtf(var + 1e-5f);
        lsc[tid] = sc;
        lsh[tid] = btPrev[tid] - m * sc;
    }
    __syncthreads();
}

// ---- layer 0: x(64) -> h0 (4 features = 2 planes) --------------------------
// 4 lanes per row, 16 cols/lane; weights in 64 VGPRs; 2-level shfl reduce.
__global__ void __launch_bounds__(NTHR) layer0(
        const float* __restrict__ x, __half2* __restrict__ hout,
        const float* __restrict__ W, const float* __restrict__ b,
        float* __restrict__ gslots) {
    __shared__ float bsum[NREP * SSTR];
    const int tid = threadIdx.x, bid = blockIdx.x;
    const int wv = tid >> 6, lane = tid & 63, grp = lane >> 2, sub = lane & 3;
    for (int i = tid; i < NREP * SSTR; i += NTHR) bsum[i] = 0.0f;

    float4 w[4][4];
    float bb[4];
#pragma unroll
    for (int o = 0; o < 4; ++o) {
        bb[o] = b[o];
#pragma unroll
        for (int q = 0; q < 4; ++q)
            w[o][q] = *(const float4*)(W + o * 64 + sub * 16 + q * 4);
    }
    float sl[4] = {0.f, 0.f, 0.f, 0.f}, ql[4] = {0.f, 0.f, 0.f, 0.f};
    __syncthreads();

    const int base = bid * 1024 + wv * 16 + grp;
#pragma unroll
    for (int pass = 0; pass < 16; ++pass) {
        const int row = base + pass * 64;
        const float* xr = x + (size_t)row * 64 + sub * 16;
        float par[4] = {0.f, 0.f, 0.f, 0.f};
#pragma unroll
        for (int q = 0; q < 4; ++q) {
            const float4 xv = *(const float4*)(xr + q * 4);
#pragma unroll
            for (int o = 0; o < 4; ++o)
                par[o] = fmaf(w[o][q].x, xv.x, fmaf(w[o][q].y, xv.y,
                          fmaf(w[o][q].z, xv.z, fmaf(w[o][q].w, xv.w, par[o]))));
        }
#pragma unroll
        for (int o = 0; o < 4; ++o) {
            par[o] += __shfl_xor(par[o], 1, 64);
            par[o] += __shfl_xor(par[o], 2, 64);
        }
        if (sub == 0) {
            float hv[4];
#pragma unroll
            for (int o = 0; o < 4; ++o) {
                hv[o] = par[o] + bb[o];
                sl[o] += hv[o];
                ql[o] = fmaf(hv[o], hv[o], ql[o]);
            }
            hout[row]          = __floats2half2_rn(hv[0], hv[1]);
            hout[BATCHN + row] = __floats2half2_rn(hv[2], hv[3]);
        }
    }
    if (sub == 0) {
        const int rep = (tid & 31) * SSTR;
#pragma unroll
        for (int o = 0; o < 4; ++o) {
            atomicAdd(&bsum[rep + o], sl[o]);
            atomicAdd(&bsum[rep + 24 + o], ql[o]);
        }
    }
    stats_deposit<4>(bsum, gslots, tid, bid);
}

// ---- layers 1..9: prologue BN params, BN+tanh fused, linear, emit planes ---
// 4 rows/thread; float4 per plane load/store.
template <int L>
__global__ void __launch_bounds__(NTHR) layer_mid(
        const __half2* __restrict__ hin, __half2* __restrict__ hout,
        const float* __restrict__ W, const float* __restrict__ b,
        const float* __restrict__ gPrev, const float* __restrict__ btPrev,
        const float* __restrict__ gsPrev, float* __restrict__ gsOut) {
    constexpr int DIN = D_[L], DOUT = D_[L + 1];
    constexpr int NPI = (DIN + 1) / 2, NPO = (DOUT + 1) / 2;
    __shared__ float2 lw[DOUT * NPI];
    __shared__ float lb[DOUT], lsc[DIN], lsh[DIN];
    __shared__ float red[2 * DIN];
    __shared__ float bsum[NREP * SSTR];
    const int tid = threadIdx.x, bid = blockIdx.x;
    for (int i = tid; i < DOUT * NPI; i += NTHR) {
        const int o = i / NPI, cp = i - o * NPI;
        const float w0 = W[o * DIN + 2 * cp];
        const float w1 = (2 * cp + 1 < DIN) ? W[o * DIN + 2 * cp + 1] : 0.0f;
        lw[i] = make_float2(w0, w1);
    }
    if (tid < DOUT) lb[tid] = b[tid];
    if (tid < 2 * DIN) red[tid] = 0.0f;
    for (int i = tid; i < NREP * SSTR; i += NTHR) bsum[i] = 0.0f;
    __syncthreads();
    slots_to_scsh<DIN>(gsPrev, gPrev, btPrev, red, lsc, lsh, tid);

    const int ei = bid * NTHR + tid;   // 4-row group index; rows 4ei..4ei+3

    // load planes (float4 = 4 rows), BN+tanh, repack
    __half2 a2[4][NPI];
#pragma unroll
    for (int cp = 0; cp < NPI; ++cp) {
        const float4 pl = ((const float4*)(hin + (size_t)cp * BATCHN))[ei];
        const __half2* h4 = (const __half2*)&pl;
#pragma unroll
        for (int r = 0; r < 4; ++r) {
            const float t0 = fast_tanh(fmaf(__low2float(h4[r]), lsc[2 * cp], lsh[2 * cp]));
            const float t1 = (2 * cp + 1 < DIN)
                ? fast_tanh(fmaf(__high2float(h4[r]), lsc[2 * cp + 1], lsh[2 * cp + 1]))
                : 0.0f;
            a2[r][cp] = __floats2half2_rn(t0, t1);
        }
    }

    const int rep = (tid & 31) * SSTR;
#pragma unroll
    for (int op = 0; op < NPO; ++op) {
        const int o0 = 2 * op, o1 = o0 + 1;
        float a0[4], a1[4];
#pragma unroll
        for (int r = 0; r < 4; ++r) {
            a0[r] = lb[o0];
            a1[r] = (o1 < DOUT) ? lb[o1] : 0.0f;
        }
#pragma unroll
        for (int cp = 0; cp < NPI; ++cp) {
            const float2 w0 = lw[o0 * NPI + cp];
            const float2 w1 = (o1 < DOUT) ? lw[o1 * NPI + cp] : make_float2(0.0f, 0.0f);
#pragma unroll
            for (int r = 0; r < 4; ++r) {
                const float x0 = __low2float(a2[r][cp]);
                const float x1 = __high2float(a2[r][cp]);
                a0[r] = fmaf(w0.x, x0, fmaf(w0.y, x1, a0[r]));
                a1[r] = fmaf(w1.x, x0, fmaf(w1.y, x1, a1[r]));
            }
        }
        {
            const float s0 = (a0[0] + a0[1]) + (a0[2] + a0[3]);
            const float q0 = fmaf(a0[0], a0[0], fmaf(a0[1], a0[1],
                              fmaf(a0[2], a0[2], a0[3] * a0[3])));
            atomicAdd(&bsum[rep + o0], s0);
            atomicAdd(&bsum[rep + 24 + o0], q0);
            if (o1 < DOUT) {
                const float s1 = (a1[0] + a1[1]) + (a1[2] + a1[3]);
                const float q1 = fmaf(a1[0], a1[0], fmaf(a1[1], a1[1],
                                  fmaf(a1[2], a1[2], a1[3] * a1[3])));
                atomicAdd(&bsum[rep + o1], s1);
                atomicAdd(&bsum[rep + 24 + o1], q1);
            }
        }
        float4 st;
        __half2* sp = (__half2*)&st;
#pragma unroll
        for (int r = 0; r < 4; ++r)
            sp[r] = __floats2half2_rn(a0[r], (o1 < DOUT) ? a1[r] : 0.0f);
        ((float4*)(hout + (size_t)op * BATCHN))[ei] = st;
    }
    stats_deposit<DOUT>(bsum, gsOut, tid, bid);
}

// ---- layer 10: prologue BN_9, tanh, linear 5->1, sigmoid -> out(f32) -------
__global__ void __launch_bounds__(NTHR) layer10(
        const __half2* __restrict__ hin, float* __restrict__ out,
        const float* __restrict__ W, const float* __restrict__ b,
        const float* __restrict__ gPrev, const float* __restrict__ btPrev,
        const float* __restrict__ gsPrev) {
    __shared__ float lw[6], lsc[6], lsh[6];
    __shared__ float red[10];
    __shared__ float lb0;
    const int tid = threadIdx.x, bid = blockIdx.x;
    if (tid < 5) lw[tid] = W[tid];
    if (tid == 5) { lw[5] = 0.0f; lsc[5] = 0.0f; lsh[5] = 0.0f; }
    if (tid == 0) lb0 = b[0];
    if (tid < 10) red[tid] = 0.0f;
    __syncthreads();
    slots_to_scsh<5>(gsPrev, gPrev, btPrev, red, lsc, lsh, tid);

    const int ei = bid * NTHR + tid;
    float a[4] = {lb0, lb0, lb0, lb0};
#pragma unroll
    for (int cp = 0; cp < 3; ++cp) {
        const float4 pl = ((const float4*)(hin + (size_t)cp * BATCHN))[ei];
        const __half2* h4 = (const __half2*)&pl;
#pragma unroll
        for (int r = 0; r < 4; ++r) {
            const float t0 = fast_tanh(fmaf(__low2float(h4[r]), lsc[2 * cp], lsh[2 * cp]));
            const float t1 = fast_tanh(fmaf(__high2float(h4[r]), lsc[2 * cp + 1], lsh[2 * cp + 1]));
            a[r] = fmaf(lw[2 * cp], t0, fmaf(lw[2 * cp + 1], t1, a[r]));
        }
    }
    float4 ov;
#pragma unroll
    for (int r = 0; r < 4; ++r) {
        const float e = exp2f(a[r] * -1.4426950408889634f);
        ((float*)&ov)[r] = __fdividef(1.0f, 1.0f + e);
    }
    ((float4*)out)[ei] = ov;
}

// zero gslots each call (graph replays do not re-poison ws)
__global__ void init_ws(float* __restrict__ gstats) {
    const int i = threadIdx.x + blockIdx.x * blockDim.x;
    if (i < 10 * NSLOT * SLOTW) gstats[i] = 0.0f;
}

extern "C" void kernel_launch(void* const* d_in, const int* in_sizes, int n_in,
                              void* d_out, int out_size, void* d_ws, size_t ws_size,
                              hipStream_t stream) {
    const float *W[11], *b[11], *g[10], *bt[10];
    const float* x = (const float*)d_in[0];
    int k = 1;
    for (int l = 0; l < 11; ++l) {
        W[l] = (const float*)d_in[k++];
        b[l] = (const float*)d_in[k++];
        if (l < 10) {
            g[l] = (const float*)d_in[k++];
            bt[l] = (const float*)d_in[k++];
        }
    }
    float* out = (float*)d_out;

    // ws layout (bytes):
    //   gstats @ 0        : 10*64*48*4 = 122880
    //   hA     @ 131072   : 5 planes x 4MB  (h0:2, h2/h4/h6:5, h8:3)
    //   hB     @ 21102592 : 10 planes x 4MB (h1:10, h3/h5/h7:5, h9:3)
    char* ws = (char*)d_ws;
    float*   gstats = (float*)ws;
    __half2* hA     = (__half2*)(ws + 131072);
    __half2* hB     = (__half2*)(ws + 131072 + 20971520);

    auto GS = [&](int L) { return gstats + (size_t)L * NSLOT * SLOTW; };

    init_ws<<<dim3(120), dim3(NTHR), 0, stream>>>(gstats);
    layer0<<<dim3(L0BLK), dim3(NTHR), 0, stream>>>(x, hA, W[0], b[0], GS(0));
    layer_mid<1><<<dim3(MIDBLK), dim3(NTHR), 0, stream>>>(hA, hB, W[1], b[1],
                                                          g[0], bt[0], GS(0), GS(1));
    layer_mid<2><<<dim3(MIDBLK), dim3(NTHR), 0, stream>>>(hB, hA, W[2], b[2],
                                                          g[1], bt[1], GS(1), GS(2));
    layer_mid<3><<<dim3(MIDBLK), dim3(NTHR), 0, stream>>>(hA, hB, W[3], b[3],
                                                          g[2], bt[2], GS(2), GS(3));
    layer_mid<4><<<dim3(MIDBLK), dim3(NTHR), 0, stream>>>(hB, hA, W[4], b[4],
                                                          g[3], bt[3], GS(3), GS(4));
    layer_mid<5><<<dim3(MIDBLK), dim3(NTHR), 0, stream>>>(hA, hB, W[5], b[5],
                                                          g[4], bt[4], GS(4), GS(5));
    layer_mid<6><<<dim3(MIDBLK), dim3(NTHR), 0, stream>>>(hB, hA, W[6], b[6],
                                                          g[5], bt[5], GS(5), GS(6));
    layer_mid<7><<<dim3(MIDBLK), dim3(NTHR), 0, stream>>>(hA, hB, W[7], b[7],
                                                          g[6], bt[6], GS(6), GS(7));
    layer_mid<8><<<dim3(MIDBLK), dim3(NTHR), 0, stream>>>(hB, hA, W[8], b[8],
                                                          g[7], bt[7], GS(7), GS(8));
    layer_mid<9><<<dim3(MIDBLK), dim3(NTHR), 0, stream>>>(hA, hB, W[9], b[9],
                                                          g[8], bt[8], GS(8), GS(9));
    layer10<<<dim3(MIDBLK), dim3(NTHR), 0, stream>>>(hB, out, W[10], b[10],
                                                     g[9], bt[9], GS(9));
}

// Round 10
// 398.270 us; speedup vs baseline: 4.0845x; 1.1021x over previous
//
#include <hip/hip_runtime.h>
#include <hip/hip_fp16.h>

// ---------------------------------------------------------------------------
// Multi-kernel MLP: 12 graph-captured launches, kernel boundary = global sync.
// R10 = R9 with the compile fix: __builtin_nontemporal_* requires a NATIVE
// vector type (clang ext_vector_type), not HIP_vector_type<float,4>.
// R9 rationale vs R8 (439us): attack the ~25us/kernel residual.
//  * ALL h-plane I/O (and x, out) uses NON-TEMPORAL loads/stores: bypass
//    per-XCD L2 so producer stores land in L3/MALL directly (no kernel-end
//    L2 writeback tax) and cross-XCD consumers hit L3 instead of miss+refill.
//  * slots_to_scsh: 16-slot register partials -> 4 LDS atomics per feature.
//  * layer0: group leaders gather h into LDS, then bulk float4/lane stores.
//  * init_ws zeroes only GS(0); kernel L's block 0 zeroes GS(L+1).
// ---------------------------------------------------------------------------

#define NTHR 256
#define BATCHN 1048576
#define L0BLK 1024     // layer0: 1024 rows/block
#define MIDBLK 1024    // mid layers: 4 rows/thread
#define NREP 32        // LDS stat replicas (stride 49 odd -> bank bijection)
#define SSTR 49
#define NSLOT 64       // global stat slots
#define SLOTW 48       // floats per slot: [0..23]=sum, [24..47]=sumsq

static_assert(L0BLK * 1024 == BATCHN, "layer0 row coverage");
static_assert(MIDBLK * NTHR * 4 == BATCHN, "mid row coverage");

static constexpr int D_[12] = {64, 4, 20, 10, 10, 10, 10, 10, 5, 5, 5, 1};

typedef float floatx4 __attribute__((ext_vector_type(4)));

__device__ __forceinline__ float fast_tanh(float x) {
    const float e = exp2f(x * 2.8853900817779268f);
    return 1.0f - __fdividef(2.0f, e + 1.0f);
}

__device__ __forceinline__ floatx4 ntld4(const void* p) {
    return __builtin_nontemporal_load((const floatx4*)p);
}
__device__ __forceinline__ void ntst4(void* p, floatx4 v) {
    __builtin_nontemporal_store(v, (floatx4*)p);
}

// ---- block-end stats deposit: LDS replicas -> one global atomic per block --
template <int DOUT>
__device__ __forceinline__ void stats_deposit(float* bsum, float* __restrict__ gslots,
                                              int tid, int bid) {
    __syncthreads();   // all LDS stat atomics done
    if (tid < 2 * DOUT) {
        const int idx = (tid < DOUT) ? tid : (24 + (tid - DOUT));
        float v = 0.0f;
        for (int r = 0; r < NREP; ++r) v += bsum[r * SSTR + idx];
        atomicAdd(&gslots[(bid & (NSLOT - 1)) * SLOTW + idx], v);   // device scope
    }
}

// ---- prologue: reduce previous layer's slots -> lsc/lsh (per block) --------
// thread (f = tid&63, c = tid>>6): register-sum 16 slots, one LDS atomic.
template <int DIN>
__device__ __forceinline__ void slots_to_scsh(const float* __restrict__ gsPrev,
                                              const float* __restrict__ gPrev,
                                              const float* __restrict__ btPrev,
                                              float* red, float* lsc, float* lsh,
                                              int tid) {
    constexpr int NF = 2 * DIN;
    const int f = tid & 63, c = tid >> 6;
    if (f < NF) {
        const int idx = (f < DIN) ? f : (24 + (f - DIN));
        float v = 0.0f;
#pragma unroll
        for (int q = 0; q < 16; ++q)
            v += gsPrev[(c * 16 + q) * SLOTW + idx];
        atomicAdd(&red[f], v);
    }
    __syncthreads();
    if (tid < DIN) {
        constexpr float inv = 1.0f / (float)BATCHN;
        const float m = red[tid] * inv;
        const float var = fmaxf(red[DIN + tid] * inv - m * m, 0.0f);
        const float sc = gPrev[tid] * rsqrtf(var + 1e-5f);
        lsc[tid] = sc;
        lsh[tid] = btPrev[tid] - m * sc;
    }
    __syncthreads();
}

// ---- layer 0: x(64) -> h0 (4 features = 2 planes) --------------------------
// 4 lanes/row, 16 cols/lane; 2-level shfl reduce; LDS gather -> bulk store.
__global__ void __launch_bounds__(NTHR) layer0(
        const float* __restrict__ x, __half2* __restrict__ hout,
        const float* __restrict__ W, const float* __restrict__ b,
        float* __restrict__ gslots, float* __restrict__ gsNext) {
    __shared__ float bsum[NREP * SSTR];
    __shared__ __half2 hs[2][1024];
    const int tid = threadIdx.x, bid = blockIdx.x;
    const int wv = tid >> 6, lane = tid & 63, grp = lane >> 2, sub = lane & 3;
    for (int i = tid; i < NREP * SSTR; i += NTHR) bsum[i] = 0.0f;
    if (bid == 0)   // zero next layer's slots (ordered by kernel boundary)
        for (int i = tid; i < NSLOT * SLOTW; i += NTHR) gsNext[i] = 0.0f;

    floatx4 w[4][4];
    float bb[4];
#pragma unroll
    for (int o = 0; o < 4; ++o) {
        bb[o] = b[o];
#pragma unroll
        for (int q = 0; q < 4; ++q)
            w[o][q] = *(const floatx4*)(W + o * 64 + sub * 16 + q * 4);
    }
    float sl[4] = {0.f, 0.f, 0.f, 0.f}, ql[4] = {0.f, 0.f, 0.f, 0.f};
    __syncthreads();

    const int rbase = bid * 1024;
#pragma unroll
    for (int pass = 0; pass < 16; ++pass) {
        const int lrow = wv * 16 + grp + pass * 64;
        const float* xr = x + (size_t)(rbase + lrow) * 64 + sub * 16;
        float par[4] = {0.f, 0.f, 0.f, 0.f};
#pragma unroll
        for (int q = 0; q < 4; ++q) {
            const floatx4 xv = ntld4(xr + q * 4);
#pragma unroll
            for (int o = 0; o < 4; ++o)
                par[o] = fmaf(w[o][q].x, xv.x, fmaf(w[o][q].y, xv.y,
                          fmaf(w[o][q].z, xv.z, fmaf(w[o][q].w, xv.w, par[o]))));
        }
#pragma unroll
        for (int o = 0; o < 4; ++o) {
            par[o] += __shfl_xor(par[o], 1, 64);
            par[o] += __shfl_xor(par[o], 2, 64);
        }
        if (sub == 0) {
            float hv[4];
#pragma unroll
            for (int o = 0; o < 4; ++o) {
                hv[o] = par[o] + bb[o];
                sl[o] += hv[o];
                ql[o] = fmaf(hv[o], hv[o], ql[o]);
            }
            hs[0][lrow] = __floats2half2_rn(hv[0], hv[1]);
            hs[1][lrow] = __floats2half2_rn(hv[2], hv[3]);
        }
    }
    if (sub == 0) {
        const int rep = (tid & 31) * SSTR;
#pragma unroll
        for (int o = 0; o < 4; ++o) {
            atomicAdd(&bsum[rep + o], sl[o]);
            atomicAdd(&bsum[rep + 24 + o], ql[o]);
        }
    }
    __syncthreads();   // hs complete
    ntst4((float*)hout + rbase + tid * 4, ((const floatx4*)hs[0])[tid]);
    ntst4((float*)(hout + BATCHN) + rbase + tid * 4, ((const floatx4*)hs[1])[tid]);
    stats_deposit<4>(bsum, gslots, tid, bid);
}

// ---- layers 1..9: prologue BN params, BN+tanh fused, linear, emit planes ---
template <int L>
__global__ void __launch_bounds__(NTHR) layer_mid(
        const __half2* __restrict__ hin, __half2* __restrict__ hout,
        const float* __restrict__ W, const float* __restrict__ b,
        const float* __restrict__ gPrev, const float* __restrict__ btPrev,
        const float* __restrict__ gsPrev, float* __restrict__ gsOut,
        float* __restrict__ gsNext) {
    constexpr int DIN = D_[L], DOUT = D_[L + 1];
    constexpr int NPI = (DIN + 1) / 2, NPO = (DOUT + 1) / 2;
    __shared__ float2 lw[DOUT * NPI];
    __shared__ float lb[DOUT], lsc[DIN], lsh[DIN];
    __shared__ float red[2 * DIN];
    __shared__ float bsum[NREP * SSTR];
    const int tid = threadIdx.x, bid = blockIdx.x;
    for (int i = tid; i < DOUT * NPI; i += NTHR) {
        const int o = i / NPI, cp = i - o * NPI;
        const float w0 = W[o * DIN + 2 * cp];
        const float w1 = (2 * cp + 1 < DIN) ? W[o * DIN + 2 * cp + 1] : 0.0f;
        lw[i] = make_float2(w0, w1);
    }
    if (tid < DOUT) lb[tid] = b[tid];
    if (tid < 2 * DIN) red[tid] = 0.0f;
    for (int i = tid; i < NREP * SSTR; i += NTHR) bsum[i] = 0.0f;
    if (gsNext && bid == 0)
        for (int i = tid; i < NSLOT * SLOTW; i += NTHR) gsNext[i] = 0.0f;
    __syncthreads();
    slots_to_scsh<DIN>(gsPrev, gPrev, btPrev, red, lsc, lsh, tid);

    const int ei = bid * NTHR + tid;   // 4-row group index; rows 4ei..4ei+3

    // load planes (float4 = 4 rows) non-temporally, BN+tanh, repack
    __half2 a2[4][NPI];
#pragma unroll
    for (int cp = 0; cp < NPI; ++cp) {
        const floatx4 pl = ntld4((const float*)(hin + (size_t)cp * BATCHN) + (size_t)ei * 4);
        const __half2* h4 = (const __half2*)&pl;
#pragma unroll
        for (int r = 0; r < 4; ++r) {
            const float t0 = fast_tanh(fmaf(__low2float(h4[r]), lsc[2 * cp], lsh[2 * cp]));
            const float t1 = (2 * cp + 1 < DIN)
                ? fast_tanh(fmaf(__high2float(h4[r]), lsc[2 * cp + 1], lsh[2 * cp + 1]))
                : 0.0f;
            a2[r][cp] = __floats2half2_rn(t0, t1);
        }
    }

    const int rep = (tid & 31) * SSTR;
#pragma unroll
    for (int op = 0; op < NPO; ++op) {
        const int o0 = 2 * op, o1 = o0 + 1;
        float a0[4], a1[4];
#pragma unroll
        for (int r = 0; r < 4; ++r) {
            a0[r] = lb[o0];
            a1[r] = (o1 < DOUT) ? lb[o1] : 0.0f;
        }
#pragma unroll
        for (int cp = 0; cp < NPI; ++cp) {
            const float2 w0 = lw[o0 * NPI + cp];
            const float2 w1 = (o1 < DOUT) ? lw[o1 * NPI + cp] : make_float2(0.0f, 0.0f);
#pragma unroll
            for (int r = 0; r < 4; ++r) {
                const float x0 = __low2float(a2[r][cp]);
                const float x1 = __high2float(a2[r][cp]);
                a0[r] = fmaf(w0.x, x0, fmaf(w0.y, x1, a0[r]));
                a1[r] = fmaf(w1.x, x0, fmaf(w1.y, x1, a1[r]));
            }
        }
        {
            const float s0 = (a0[0] + a0[1]) + (a0[2] + a0[3]);
            const float q0 = fmaf(a0[0], a0[0], fmaf(a0[1], a0[1],
                              fmaf(a0[2], a0[2], a0[3] * a0[3])));
            atomicAdd(&bsum[rep + o0], s0);
            atomicAdd(&bsum[rep + 24 + o0], q0);
            if (o1 < DOUT) {
                const float s1 = (a1[0] + a1[1]) + (a1[2] + a1[3]);
                const float q1 = fmaf(a1[0], a1[0], fmaf(a1[1], a1[1],
                                  fmaf(a1[2], a1[2], a1[3] * a1[3])));
                atomicAdd(&bsum[rep + o1], s1);
                atomicAdd(&bsum[rep + 24 + o1], q1);
            }
        }
        floatx4 st;
        __half2* sp = (__half2*)&st;
#pragma unroll
        for (int r = 0; r < 4; ++r)
            sp[r] = __floats2half2_rn(a0[r], (o1 < DOUT) ? a1[r] : 0.0f);
        ntst4((float*)(hout + (size_t)op * BATCHN) + (size_t)ei * 4, st);
    }
    stats_deposit<DOUT>(bsum, gsOut, tid, bid);
}

// ---- layer 10: prologue BN_9, tanh, linear 5->1, sigmoid -> out(f32) -------
__global__ void __launch_bounds__(NTHR) layer10(
        const __half2* __restrict__ hin, float* __restrict__ out,
        const float* __restrict__ W, const float* __restrict__ b,
        const float* __restrict__ gPrev, const float* __restrict__ btPrev,
        const float* __restrict__ gsPrev) {
    __shared__ float lw[6], lsc[6], lsh[6];
    __shared__ float red[10];
    __shared__ float lb0;
    const int tid = threadIdx.x, bid = blockIdx.x;
    if (tid < 5) lw[tid] = W[tid];
    if (tid == 5) { lw[5] = 0.0f; lsc[5] = 0.0f; lsh[5] = 0.0f; }
    if (tid == 0) lb0 = b[0];
    if (tid < 10) red[tid] = 0.0f;
    __syncthreads();
    slots_to_scsh<5>(gsPrev, gPrev, btPrev, red, lsc, lsh, tid);

    const int ei = bid * NTHR + tid;
    float a[4] = {lb0, lb0, lb0, lb0};
#pragma unroll
    for (int cp = 0; cp < 3; ++cp) {
        const floatx4 pl = ntld4((const float*)(hin + (size_t)cp * BATCHN) + (size_t)ei * 4);
        const __half2* h4 = (const __half2*)&pl;
#pragma unroll
        for (int r = 0; r < 4; ++r) {
            const float t0 = fast_tanh(fmaf(__low2float(h4[r]), lsc[2 * cp], lsh[2 * cp]));
            const float t1 = fast_tanh(fmaf(__high2float(h4[r]), lsc[2 * cp + 1], lsh[2 * cp + 1]));
            a[r] = fmaf(lw[2 * cp], t0, fmaf(lw[2 * cp + 1], t1, a[r]));
        }
    }
    floatx4 ov;
#pragma unroll
    for (int r = 0; r < 4; ++r) {
        const float e = exp2f(a[r] * -1.4426950408889634f);
        ov[r] = __fdividef(1.0f, 1.0f + e);
    }
    ntst4(out + (size_t)ei * 4, ov);
}

// zero GS(0) only; GS(L+1) is zeroed by kernel L's block 0.
__global__ void init_ws(float* __restrict__ gs0) {
    const int i = threadIdx.x + blockIdx.x * blockDim.x;
    if (i < NSLOT * SLOTW) gs0[i] = 0.0f;
}

extern "C" void kernel_launch(void* const* d_in, const int* in_sizes, int n_in,
                              void* d_out, int out_size, void* d_ws, size_t ws_size,
                              hipStream_t stream) {
    const float *W[11], *b[11], *g[10], *bt[10];
    const float* x = (const float*)d_in[0];
    int k = 1;
    for (int l = 0; l < 11; ++l) {
        W[l] = (const float*)d_in[k++];
        b[l] = (const float*)d_in[k++];
        if (l < 10) {
            g[l] = (const float*)d_in[k++];
            bt[l] = (const float*)d_in[k++];
        }
    }
    float* out = (float*)d_out;

    // ws layout (bytes):
    //   gstats @ 0        : 10*64*48*4 = 122880
    //   hA     @ 131072   : 5 planes x 4MB  (h0:2, h2/h4/h6:5, h8:3)
    //   hB     @ 21102592 : 10 planes x 4MB (h1:10, h3/h5/h7:5, h9:3)
    char* ws = (char*)d_ws;
    float*   gstats = (float*)ws;
    __half2* hA     = (__half2*)(ws + 131072);
    __half2* hB     = (__half2*)(ws + 131072 + 20971520);

    auto GS = [&](int L) { return gstats + (size_t)L * NSLOT * SLOTW; };

    init_ws<<<dim3(12), dim3(NTHR), 0, stream>>>(GS(0));
    layer0<<<dim3(L0BLK), dim3(NTHR), 0, stream>>>(x, hA, W[0], b[0], GS(0), GS(1));
    layer_mid<1><<<dim3(MIDBLK), dim3(NTHR), 0, stream>>>(hA, hB, W[1], b[1],
                                                          g[0], bt[0], GS(0), GS(1), GS(2));
    layer_mid<2><<<dim3(MIDBLK), dim3(NTHR), 0, stream>>>(hB, hA, W[2], b[2],
                                                          g[1], bt[1], GS(1), GS(2), GS(3));
    layer_mid<3><<<dim3(MIDBLK), dim3(NTHR), 0, stream>>>(hA, hB, W[3], b[3],
                                                          g[2], bt[2], GS(2), GS(3), GS(4));
    layer_mid<4><<<dim3(MIDBLK), dim3(NTHR), 0, stream>>>(hB, hA, W[4], b[4],
                                                          g[3], bt[3], GS(3), GS(4), GS(5));
    layer_mid<5><<<dim3(MIDBLK), dim3(NTHR), 0, stream>>>(hA, hB, W[5], b[5],
                                                          g[4], bt[4], GS(4), GS(5), GS(6));
    layer_mid<6><<<dim3(MIDBLK), dim3(NTHR), 0, stream>>>(hB, hA, W[6], b[6],
                                                          g[5], bt[5], GS(5), GS(6), GS(7));
    layer_mid<7><<<dim3(MIDBLK), dim3(NTHR), 0, stream>>>(hA, hB, W[7], b[7],
                                                          g[6], bt[6], GS(6), GS(7), GS(8));
    layer_mid<8><<<dim3(MIDBLK), dim3(NTHR), 0, stream>>>(hB, hA, W[8], b[8],
                                                          g[7], bt[7], GS(7), GS(8), GS(9));
    layer_mid<9><<<dim3(MIDBLK), dim3(NTHR), 0, stream>>>(hA, hB, W[9], b[9],
                                                          g[8], bt[8], GS(8), GS(9), nullptr);
    layer10<<<dim3(MIDBLK), dim3(NTHR), 0, stream>>>(hB, out, W[10], b[10],
                                                     g[9], bt[9], GS(9));
}